// Round 1
// baseline (2651.660 us; speedup 1.0000x reference)
//
#include <hip/hip_runtime.h>
#include <math.h>

#define NN 100000
#define NE 1200000
#define INCH 128
#define HIDD 256
#define OUTC 64
#define NDIFF 1000

__device__ __forceinline__ float softplusf_(float x) {
  return fmaxf(x, 0.f) + logf(1.f + __expf(-fabsf(x)));
}
__device__ __forceinline__ float sigmoidf_(float x) {
  return 1.f / (1.f + __expf(-x));
}
__device__ __forceinline__ float tanhf_fast(float x) {
  float ax = fabsf(x);
  float e = __expf(-2.f * ax);
  float t = (1.f - e) / (1.f + e);
  return x < 0.f ? -t : t;
}

// ---------------- setup kernels ----------------

__global__ void zero_kernel(int* __restrict__ p, int n) {
  int i = blockIdx.x * 256 + threadIdx.x;
  if (i < n) p[i] = 0;
}

__global__ void count_kernel(const int* __restrict__ dst, int* __restrict__ deg) {
  int e = blockIdx.x * 256 + threadIdx.x;
  if (e < NE) atomicAdd(&deg[dst[e]], 1);
}

// Build transposed weight layouts for coalesced B reads.
// W1t[k*256+j] = lin1_w[j*128+k]           (128x256)
// W2t[k*64+j]  = lin2_w[j*256+k]           (256x64)
// Wct[k*256+j]: combined GRU weights, input = [m(64) | h(64)], cols:
//   j in [0,64):    r-gate    = w_ih[j][k] (k<64) else w_hh[j][k-64]
//   j in [64,128):  z-gate    = w_ih[64+jj][..] / w_hh[64+jj][..]
//   j in [128,192): gi_n      = w_ih[128+jj][k] (k<64) else 0
//   j in [192,256): gh_n      = 0 (k<64) else w_hh[128+jj][k-64]
__global__ void prep_w_kernel(const float* __restrict__ lin1_w, const float* __restrict__ lin2_w,
                              const float* __restrict__ w_ih, const float* __restrict__ w_hh,
                              float* __restrict__ W1t, float* __restrict__ W2t, float* __restrict__ Wct) {
  int i = blockIdx.x * 256 + threadIdx.x;  // 0..32767
  if (i < 128 * 256) {
    int k = i >> 8, j = i & 255;
    W1t[i] = lin1_w[j * 128 + k];
  }
  if (i < 256 * 64) {
    int k = i >> 6, j = i & 63;
    W2t[i] = lin2_w[j * 256 + k];
  }
  if (i < 128 * 256) {
    int k = i >> 8, j = i & 255;
    int g = j >> 6, jj = j & 63;
    float v;
    if (g == 0)      v = (k < 64) ? w_ih[jj * 64 + k]         : w_hh[jj * 64 + (k - 64)];
    else if (g == 1) v = (k < 64) ? w_ih[(64 + jj) * 64 + k]  : w_hh[(64 + jj) * 64 + (k - 64)];
    else if (g == 2) v = (k < 64) ? w_ih[(128 + jj) * 64 + k] : 0.f;
    else             v = (k < 64) ? 0.f                       : w_hh[(128 + jj) * 64 + (k - 64)];
    Wct[i] = v;
  }
}

// ---------------- exclusive scan (3 kernels, 1024 elems/block) ----------------

__global__ void scanA_kernel(const int* __restrict__ deg, int* __restrict__ rowptr,
                             int* __restrict__ blockSums) {
  int t = threadIdx.x;
  int base = blockIdx.x * 1024 + t * 4;
  int d0 = (base + 0 < NN) ? deg[base + 0] : 0;
  int d1 = (base + 1 < NN) ? deg[base + 1] : 0;
  int d2 = (base + 2 < NN) ? deg[base + 2] : 0;
  int d3 = (base + 3 < NN) ? deg[base + 3] : 0;
  int s = d0 + d1 + d2 + d3;
  int lane = t & 63;
  int incl = s;
  #pragma unroll
  for (int o = 1; o < 64; o <<= 1) {
    int v = __shfl_up(incl, o, 64);
    if (lane >= o) incl += v;
  }
  __shared__ int wsum[4], woff[4];
  if (lane == 63) wsum[t >> 6] = incl;
  __syncthreads();
  if (t == 0) {
    int r = 0;
    for (int w = 0; w < 4; ++w) { woff[w] = r; r += wsum[w]; }
    blockSums[blockIdx.x] = r;
  }
  __syncthreads();
  int run = woff[t >> 6] + incl - s;
  int dd[4] = {d0, d1, d2, d3};
  #pragma unroll
  for (int q = 0; q < 4; ++q) {
    int idx = base + q;
    if (idx <= NN) rowptr[idx] = run;
    run += dd[q];
  }
}

__global__ void scanB_kernel(const int* __restrict__ blockSums, int* __restrict__ blockOff, int nblk) {
  __shared__ int v[128];
  int t = threadIdx.x;
  int mine = (t < nblk) ? blockSums[t] : 0;
  v[t] = mine;
  __syncthreads();
  for (int o = 1; o < 128; o <<= 1) {
    int add = (t >= o) ? v[t - o] : 0;
    __syncthreads();
    v[t] += add;
    __syncthreads();
  }
  if (t < nblk) blockOff[t] = v[t] - mine;
}

__global__ void scanC_kernel(int* __restrict__ rowptr, const int* __restrict__ blockOff) {
  int t = threadIdx.x;
  int base = blockIdx.x * 1024 + t * 4;
  int add = blockOff[blockIdx.x];
  #pragma unroll
  for (int q = 0; q < 4; ++q) {
    int idx = base + q;
    if (idx <= NN) rowptr[idx] += add;
  }
}

__global__ void fill_kernel(const int* __restrict__ src, const int* __restrict__ dst,
                            const int* __restrict__ etype, const float* __restrict__ etw,
                            const int* __restrict__ rowptr, int* __restrict__ cursor,
                            int* __restrict__ csr_src, float* __restrict__ csr_w) {
  int e = blockIdx.x * 256 + threadIdx.x;
  if (e >= NE) return;
  int d = dst[e];
  int pos = rowptr[d] + atomicAdd(&cursor[d], 1);
  csr_src[pos] = src[e];
  csr_w[pos] = softplusf_(etw[etype[e]]);
}

// ---------------- fused 2-layer input MLP ----------------
// h = relu(x @ W1^T + b1) @ W2^T + b2 ; tile: 32 nodes/block, 256 threads

__launch_bounds__(256, 2)
__global__ void mlp_kernel(const float* __restrict__ x,
                           const float* __restrict__ W1t, const float* __restrict__ b1,
                           const float* __restrict__ W2t, const float* __restrict__ b2,
                           float* __restrict__ h) {
  __shared__ float As[32 * 128];   // x tile / reused as B2 staging
  __shared__ float Hs[32 * 256];   // hidden
  __shared__ float Bs[32 * 256];   // B chunk (32 k x 256 cols)
  int t = threadIdx.x;
  int nb = blockIdx.x * 32;
  #pragma unroll
  for (int r = 0; r < 4; ++r) {
    int f = (r * 256 + t) * 4;
    *(float4*)&As[f] = *(const float4*)&x[nb * INCH + f];
  }
  int cg = t & 63, ig = t >> 6;
  int c0 = cg * 4, i0 = ig * 8;
  float acc[8][4];
  #pragma unroll
  for (int i = 0; i < 8; ++i)
    #pragma unroll
    for (int c = 0; c < 4; ++c) acc[i][c] = 0.f;

  for (int kc = 0; kc < 128; kc += 32) {
    __syncthreads();
    #pragma unroll
    for (int r = 0; r < 8; ++r) {
      int f = (r * 256 + t) * 4;
      *(float4*)&Bs[f] = *(const float4*)&W1t[kc * 256 + f];
    }
    __syncthreads();
    #pragma unroll
    for (int k = 0; k < 32; k += 4) {
      float4 b0 = *(const float4*)&Bs[(k + 0) * 256 + c0];
      float4 b1v = *(const float4*)&Bs[(k + 1) * 256 + c0];
      float4 b2v = *(const float4*)&Bs[(k + 2) * 256 + c0];
      float4 b3v = *(const float4*)&Bs[(k + 3) * 256 + c0];
      #pragma unroll
      for (int i = 0; i < 8; ++i) {
        float4 a = *(const float4*)&As[(i0 + i) * 128 + kc + k];
        acc[i][0] += a.x * b0.x + a.y * b1v.x + a.z * b2v.x + a.w * b3v.x;
        acc[i][1] += a.x * b0.y + a.y * b1v.y + a.z * b2v.y + a.w * b3v.y;
        acc[i][2] += a.x * b0.z + a.y * b1v.z + a.z * b2v.z + a.w * b3v.z;
        acc[i][3] += a.x * b0.w + a.y * b1v.w + a.z * b2v.w + a.w * b3v.w;
      }
    }
  }
  float4 bb = *(const float4*)&b1[c0];
  #pragma unroll
  for (int i = 0; i < 8; ++i) {
    float4 v;
    v.x = fmaxf(acc[i][0] + bb.x, 0.f);
    v.y = fmaxf(acc[i][1] + bb.y, 0.f);
    v.z = fmaxf(acc[i][2] + bb.z, 0.f);
    v.w = fmaxf(acc[i][3] + bb.w, 0.f);
    *(float4*)&Hs[(i0 + i) * 256 + c0] = v;
  }
  // layer 2: 64 cols, 8 nodes/thread; reuse As for 64x64 B chunk
  int j = t & 63;
  int i0b = (t >> 6) * 8;
  float acc2[8];
  #pragma unroll
  for (int i = 0; i < 8; ++i) acc2[i] = 0.f;
  for (int kc = 0; kc < 256; kc += 64) {
    __syncthreads();   // also covers Hs write -> read on first iter
    #pragma unroll
    for (int r = 0; r < 4; ++r) {
      int f = (r * 256 + t) * 4;
      *(float4*)&As[f] = *(const float4*)&W2t[kc * 64 + f];
    }
    __syncthreads();
    #pragma unroll
    for (int k = 0; k < 64; k += 4) {
      float w0 = As[(k + 0) * 64 + j];
      float w1 = As[(k + 1) * 64 + j];
      float w2 = As[(k + 2) * 64 + j];
      float w3 = As[(k + 3) * 64 + j];
      #pragma unroll
      for (int i = 0; i < 8; ++i) {
        float4 hv = *(const float4*)&Hs[(i0b + i) * 256 + kc + k];
        acc2[i] += hv.x * w0 + hv.y * w1 + hv.z * w2 + hv.w * w3;
      }
    }
  }
  float bj = b2[j];
  #pragma unroll
  for (int i = 0; i < 8; ++i)
    h[(nb + i0b + i) * 64 + j] = acc2[i] + bj;
}

// ---------------- scatter-mean aggregation: one wave per node ----------------

__launch_bounds__(256)
__global__ void agg_kernel(const float* __restrict__ h, const int* __restrict__ rowptr,
                           const int* __restrict__ csr_src, const float* __restrict__ csr_w,
                           float* __restrict__ m) {
  int node = (blockIdx.x * 256 + threadIdx.x) >> 6;
  int lane = threadIdx.x & 63;
  int s = rowptr[node], e = rowptr[node + 1];
  float acc = 0.f;
  for (int p = s; p < e; ++p) {
    int src = csr_src[p];
    float w = csr_w[p];
    acc += w * h[src * 64 + lane];
  }
  float cnt = (float)(e - s);
  m[node * 64 + lane] = acc / fmaxf(cnt, 1.f);
}

// ---------------- fused GRU: combined GEMM [m|h] @ Wc + gate epilogue ----------------

__launch_bounds__(256, 2)
__global__ void gru_kernel(const float* __restrict__ mi, const float* __restrict__ hin,
                           const float* __restrict__ Wct,
                           const float* __restrict__ b_ih, const float* __restrict__ b_hh,
                           float* __restrict__ hout) {
  __shared__ float As[32 * 128];
  __shared__ float Gs[32 * 256];
  __shared__ float Bs[32 * 256];
  int t = threadIdx.x;
  int nb = blockIdx.x * 32;
  #pragma unroll
  for (int r = 0; r < 4; ++r) {
    int f = (r * 256 + t) * 4;
    int i = f >> 7, k = f & 127;
    int node = nb + i;
    float4 v;
    if (k < 64) v = *(const float4*)&mi[node * 64 + k];
    else        v = *(const float4*)&hin[node * 64 + (k - 64)];
    *(float4*)&As[f] = v;
  }
  int cg = t & 63, ig = t >> 6;
  int c0 = cg * 4, i0 = ig * 8;
  float acc[8][4];
  #pragma unroll
  for (int i = 0; i < 8; ++i)
    #pragma unroll
    for (int c = 0; c < 4; ++c) acc[i][c] = 0.f;

  for (int kc = 0; kc < 128; kc += 32) {
    __syncthreads();
    #pragma unroll
    for (int r = 0; r < 8; ++r) {
      int f = (r * 256 + t) * 4;
      *(float4*)&Bs[f] = *(const float4*)&Wct[kc * 256 + f];
    }
    __syncthreads();
    #pragma unroll
    for (int k = 0; k < 32; k += 4) {
      float4 b0 = *(const float4*)&Bs[(k + 0) * 256 + c0];
      float4 b1v = *(const float4*)&Bs[(k + 1) * 256 + c0];
      float4 b2v = *(const float4*)&Bs[(k + 2) * 256 + c0];
      float4 b3v = *(const float4*)&Bs[(k + 3) * 256 + c0];
      #pragma unroll
      for (int i = 0; i < 8; ++i) {
        float4 a = *(const float4*)&As[(i0 + i) * 128 + kc + k];
        acc[i][0] += a.x * b0.x + a.y * b1v.x + a.z * b2v.x + a.w * b3v.x;
        acc[i][1] += a.x * b0.y + a.y * b1v.y + a.z * b2v.y + a.w * b3v.y;
        acc[i][2] += a.x * b0.z + a.y * b1v.z + a.z * b2v.z + a.w * b3v.z;
        acc[i][3] += a.x * b0.w + a.y * b1v.w + a.z * b2v.w + a.w * b3v.w;
      }
    }
  }
  #pragma unroll
  for (int i = 0; i < 8; ++i) {
    float4 v;
    v.x = acc[i][0]; v.y = acc[i][1]; v.z = acc[i][2]; v.w = acc[i][3];
    *(float4*)&Gs[(i0 + i) * 256 + c0] = v;
  }
  __syncthreads();
  int j = t & 63;
  int i0b = (t >> 6) * 8;
  float bir = b_ih[j] + b_hh[j];
  float biz = b_ih[64 + j] + b_hh[64 + j];
  float bin_ = b_ih[128 + j];
  float bhn = b_hh[128 + j];
  #pragma unroll
  for (int i = 0; i < 8; ++i) {
    int node = nb + i0b + i;
    const float* g = &Gs[(i0b + i) * 256];
    float r = sigmoidf_(g[j] + bir);
    float z = sigmoidf_(g[64 + j] + biz);
    float n = tanhf_fast(g[128 + j] + bin_ + r * (g[192 + j] + bhn));
    float hp = hin[node * 64 + j];
    hout[node * 64 + j] = (1.f - z) * n + z * hp;
  }
}

// ---------------- pooling + head ----------------

__global__ void scatter_kernel(const int* __restrict__ diff, int* __restrict__ flag) {
  int i = blockIdx.x * 256 + threadIdx.x;
  if (i < NDIFF) flag[diff[i]] = 1;
}

__global__ void pool_kernel(const float* __restrict__ h, const int* __restrict__ flag,
                            float* __restrict__ pooled) {
  int gw = (blockIdx.x * 256 + threadIdx.x) >> 6;
  int lane = threadIdx.x & 63;
  int nw = (gridDim.x * 256) >> 6;
  float base = 0.f, fl = 0.f, cnt = 0.f;
  for (int n = gw; n < NN; n += nw) {
    float v = h[n * 64 + lane];
    int f = flag[n];
    base += v;
    if (f) { fl += v; cnt += 1.f; }
  }
  atomicAdd(&pooled[lane], base);
  atomicAdd(&pooled[64 + lane], fl);
  if (lane == 0) atomicAdd(&pooled[128], cnt);
}

__global__ void final_kernel(const float* __restrict__ pooled,
                             const float* __restrict__ fc1_w, const float* __restrict__ fc1_b,
                             const float* __restrict__ fc2_w, const float* __restrict__ fc2_b,
                             const float* __restrict__ w_imp, float* __restrict__ out) {
  __shared__ float p[64];
  __shared__ float hid[256];
  __shared__ float o[2];
  int t = threadIdx.x;
  float wpos = softplusf_(w_imp[0]);
  if (t < 64) {
    float num = pooled[t] + wpos * pooled[64 + t];
    float den = (float)NN + wpos * pooled[128];
    p[t] = num / den;
  }
  __syncthreads();
  {
    float a = 0.f;
    for (int k = 0; k < 64; ++k) a += p[k] * fc1_w[t * 64 + k];
    hid[t] = fmaxf(a + fc1_b[t], 0.f);
  }
  __syncthreads();
  if (t < 2) {
    float a = 0.f;
    for (int k = 0; k < 256; ++k) a += hid[k] * fc2_w[t * 256 + k];
    o[t] = a + fc2_b[t];
  }
  __syncthreads();
  if (t == 0) {
    float mx = fmaxf(o[0], o[1]);
    float lse = mx + logf(__expf(o[0] - mx) + __expf(o[1] - mx));
    out[0] = o[0] - lse;
    out[1] = o[1] - lse;
  }
}

// ---------------- launch ----------------

extern "C" void kernel_launch(void* const* d_in, const int* in_sizes, int n_in,
                              void* d_out, int out_size, void* d_ws, size_t ws_size,
                              hipStream_t stream) {
  const float* x        = (const float*)d_in[0];
  const int*   ei       = (const int*)d_in[1];   // [2, NE]: src row, dst row
  const int*   etype    = (const int*)d_in[2];
  const int*   diff_idx = (const int*)d_in[3];
  const float* lin1_w   = (const float*)d_in[4];
  const float* lin1_b   = (const float*)d_in[5];
  const float* lin2_w   = (const float*)d_in[6];
  const float* lin2_b   = (const float*)d_in[7];
  const float* gru_w_ih = (const float*)d_in[8];
  const float* gru_w_hh = (const float*)d_in[9];
  const float* gru_b_ih = (const float*)d_in[10];
  const float* gru_b_hh = (const float*)d_in[11];
  const float* etw      = (const float*)d_in[12];
  const float* fc1_w    = (const float*)d_in[13];
  const float* fc1_b    = (const float*)d_in[14];
  const float* fc2_w    = (const float*)d_in[15];
  const float* fc2_b    = (const float*)d_in[16];
  const float* w_imp    = (const float*)d_in[17];
  float* out = (float*)d_out;

  char* ws = (char*)d_ws;
  size_t off = 0;
  auto alloc = [&](size_t bytes) -> void* {
    void* p = ws + off;
    off += (bytes + 255) & ~(size_t)255;
    return p;
  };
  float* h0      = (float*)alloc((size_t)NN * 64 * 4);
  float* h1      = (float*)alloc((size_t)NN * 64 * 4);
  float* mbuf    = (float*)alloc((size_t)NN * 64 * 4);
  int*   csr_src = (int*)  alloc((size_t)NE * 4);
  float* csr_w   = (float*)alloc((size_t)NE * 4);
  float* W1t     = (float*)alloc(128 * 256 * 4);
  float* W2t     = (float*)alloc(256 * 64 * 4);
  float* Wct     = (float*)alloc(128 * 256 * 4);
  int*   rowptr  = (int*)  alloc((size_t)(NN + 1) * 4);
  int*   blockSums = (int*)alloc(128 * 4);
  int*   blockOff  = (int*)alloc(128 * 4);
  int*   zbase   = (int*)  alloc((size_t)(3 * NN + 129) * 4);
  int* deg    = zbase;
  int* cursor = zbase + NN;
  int* flag   = zbase + 2 * NN;
  float* pooled = (float*)(zbase + 3 * NN);  // 64 base + 64 flagged + 1 count

  const int nscan = (NN + 1023) / 1024;  // 98

  zero_kernel<<<(3 * NN + 129 + 255) / 256, 256, 0, stream>>>(zbase, 3 * NN + 129);
  prep_w_kernel<<<128, 256, 0, stream>>>(lin1_w, lin2_w, gru_w_ih, gru_w_hh, W1t, W2t, Wct);
  count_kernel<<<(NE + 255) / 256, 256, 0, stream>>>(ei + NE, deg);
  scanA_kernel<<<nscan, 256, 0, stream>>>(deg, rowptr, blockSums);
  scanB_kernel<<<1, 128, 0, stream>>>(blockSums, blockOff, nscan);
  scanC_kernel<<<nscan, 256, 0, stream>>>(rowptr, blockOff);
  fill_kernel<<<(NE + 255) / 256, 256, 0, stream>>>(ei, ei + NE, etype, etw, rowptr, cursor,
                                                    csr_src, csr_w);
  mlp_kernel<<<NN / 32, 256, 0, stream>>>(x, W1t, lin1_b, W2t, lin2_b, h0);

  float* ha = h0;  // current h
  float* hb = h1;  // next h
  for (int it = 0; it < 3; ++it) {
    agg_kernel<<<NN / 4, 256, 0, stream>>>(ha, rowptr, csr_src, csr_w, mbuf);
    gru_kernel<<<NN / 32, 256, 0, stream>>>(mbuf, ha, Wct, gru_b_ih, gru_b_hh, hb);
    float* tmp = ha; ha = hb; hb = tmp;
  }
  scatter_kernel<<<(NDIFF + 255) / 256, 256, 0, stream>>>(diff_idx, flag);
  pool_kernel<<<256, 256, 0, stream>>>(ha, flag, pooled);
  final_kernel<<<1, 256, 0, stream>>>(pooled, fc1_w, fc1_b, fc2_w, fc2_b, w_imp, out);
}

// Round 2
// 919.537 us; speedup vs baseline: 2.8837x; 2.8837x over previous
//
#include <hip/hip_runtime.h>
#include <math.h>

#define NN 100000
#define NE 1200000
#define INCH 128
#define NDIFF 1000

typedef short short8 __attribute__((ext_vector_type(8)));
typedef float floatx4 __attribute__((ext_vector_type(4)));
typedef unsigned short ushort_t;

__device__ __forceinline__ float softplusf_(float x) {
  return fmaxf(x, 0.f) + logf(1.f + __expf(-fabsf(x)));
}
__device__ __forceinline__ float sigmoidf_(float x) {
  return 1.f / (1.f + __expf(-x));
}
__device__ __forceinline__ float tanhf_fast(float x) {
  float ax = fabsf(x);
  float e = __expf(-2.f * ax);
  float t = (1.f - e) / (1.f + e);
  return x < 0.f ? -t : t;
}
__device__ __forceinline__ ushort_t f2bf(float f) {
  unsigned u = __float_as_uint(f);
  unsigned r = (u + 0x7FFFu + ((u >> 16) & 1u)) >> 16;
  return (ushort_t)r;
}
__device__ __forceinline__ float bf2f(ushort_t s) {
  return __uint_as_float(((unsigned)s) << 16);
}

// ---------------- setup kernels ----------------

__global__ void zero_kernel(int* __restrict__ p, int n) {
  int i = blockIdx.x * 256 + threadIdx.x;
  if (i < n) p[i] = 0;
}

__global__ void count_kernel(const int* __restrict__ dst, int* __restrict__ deg) {
  int e = blockIdx.x * 256 + threadIdx.x;
  if (e < NE) atomicAdd(&deg[dst[e]], 1);
}

// bf16 weight prep, all in natural [out][in] layout (B-fragment friendly):
//  W1b [256][128] = lin1_w cast
//  W2b [64][256]  = lin2_w cast
//  Wcb [256][128] combined GRU: input = [m(64)|h(64)], rows: r(64), z(64), gi_n(64), gh_n(64)
__global__ void prep_w_kernel(const float* __restrict__ lin1_w, const float* __restrict__ lin2_w,
                              const float* __restrict__ w_ih, const float* __restrict__ w_hh,
                              ushort_t* __restrict__ W1b, ushort_t* __restrict__ W2b,
                              ushort_t* __restrict__ Wcb) {
  int i = blockIdx.x * 256 + threadIdx.x;  // 0..32767
  if (i < 128 * 256) W1b[i] = f2bf(lin1_w[i]);
  if (i < 64 * 256)  W2b[i] = f2bf(lin2_w[i]);
  if (i < 128 * 256) {
    int j = i >> 7, k = i & 127;
    float v;
    if (j < 128)      v = (k < 64) ? w_ih[j * 64 + k] : w_hh[j * 64 + (k - 64)];
    else if (j < 192) v = (k < 64) ? w_ih[j * 64 + k] : 0.f;
    else              v = (k < 64) ? 0.f : w_hh[(j - 64) * 64 + (k - 64)];
    Wcb[i] = f2bf(v);
  }
}

// ---------------- exclusive scan (3 kernels) ----------------

__global__ void scanA_kernel(const int* __restrict__ deg, int* __restrict__ rowptr,
                             int* __restrict__ blockSums) {
  int t = threadIdx.x;
  int base = blockIdx.x * 1024 + t * 4;
  int d0 = (base + 0 < NN) ? deg[base + 0] : 0;
  int d1 = (base + 1 < NN) ? deg[base + 1] : 0;
  int d2 = (base + 2 < NN) ? deg[base + 2] : 0;
  int d3 = (base + 3 < NN) ? deg[base + 3] : 0;
  int s = d0 + d1 + d2 + d3;
  int lane = t & 63;
  int incl = s;
  #pragma unroll
  for (int o = 1; o < 64; o <<= 1) {
    int v = __shfl_up(incl, o, 64);
    if (lane >= o) incl += v;
  }
  __shared__ int wsum[4], woff[4];
  if (lane == 63) wsum[t >> 6] = incl;
  __syncthreads();
  if (t == 0) {
    int r = 0;
    for (int w = 0; w < 4; ++w) { woff[w] = r; r += wsum[w]; }
    blockSums[blockIdx.x] = r;
  }
  __syncthreads();
  int run = woff[t >> 6] + incl - s;
  int dd[4] = {d0, d1, d2, d3};
  #pragma unroll
  for (int q = 0; q < 4; ++q) {
    int idx = base + q;
    if (idx <= NN) rowptr[idx] = run;
    run += dd[q];
  }
}

__global__ void scanB_kernel(const int* __restrict__ blockSums, int* __restrict__ blockOff, int nblk) {
  __shared__ int v[128];
  int t = threadIdx.x;
  int mine = (t < nblk) ? blockSums[t] : 0;
  v[t] = mine;
  __syncthreads();
  for (int o = 1; o < 128; o <<= 1) {
    int add = (t >= o) ? v[t - o] : 0;
    __syncthreads();
    v[t] += add;
    __syncthreads();
  }
  if (t < nblk) blockOff[t] = v[t] - mine;
}

__global__ void scanC_kernel(int* __restrict__ rowptr, const int* __restrict__ blockOff) {
  int t = threadIdx.x;
  int base = blockIdx.x * 1024 + t * 4;
  int add = blockOff[blockIdx.x];
  #pragma unroll
  for (int q = 0; q < 4; ++q) {
    int idx = base + q;
    if (idx <= NN) rowptr[idx] += add;
  }
}

__global__ void fill_kernel(const int* __restrict__ src, const int* __restrict__ dst,
                            const int* __restrict__ etype, const float* __restrict__ etw,
                            const int* __restrict__ rowptr, int* __restrict__ cursor,
                            int* __restrict__ csr_src, float* __restrict__ csr_w) {
  int e = blockIdx.x * 256 + threadIdx.x;
  if (e >= NE) return;
  int d = dst[e];
  int pos = rowptr[d] + atomicAdd(&cursor[d], 1);
  csr_src[pos] = src[e];
  csr_w[pos] = softplusf_(etw[etype[e]]);
}

// ---------------- fused 2-layer MLP, MFMA bf16 ----------------
// 64 rows/block, 4 waves; wave w owns rows w*16..w*16+15 for ALL columns.
// 16x16x32 layouts: A[m=lane&15][k=quad*8+j], B[n=lane&15][k=quad*8+j],
// C/D: col=lane&15, row=quad*4+reg.

__launch_bounds__(256)
__global__ void mlp_kernel(const float* __restrict__ x,
                           const ushort_t* __restrict__ W1b, const float* __restrict__ b1,
                           const ushort_t* __restrict__ W2b, const float* __restrict__ b2,
                           ushort_t* __restrict__ h) {
  __shared__ ushort_t Hs[64 * 264];  // hidden tile, stride 264 (bank-friendly)
  int t = threadIdx.x;
  int wv = t >> 6, lane = t & 63;
  int quad = lane >> 4, l15 = lane & 15;
  int nb = blockIdx.x * 64;
  int rowA = min(nb + wv * 16 + l15, NN - 1);

  floatx4 acc1[16];
  #pragma unroll
  for (int i = 0; i < 16; ++i) acc1[i] = (floatx4)0.f;

  #pragma unroll
  for (int s = 0; s < 4; ++s) {
    const float* xp = &x[(size_t)rowA * 128 + s * 32 + quad * 8];
    float4 a0 = *(const float4*)xp;
    float4 a1 = *(const float4*)(xp + 4);
    union { short8 v; ushort_t u[8]; } af;
    af.u[0] = f2bf(a0.x); af.u[1] = f2bf(a0.y); af.u[2] = f2bf(a0.z); af.u[3] = f2bf(a0.w);
    af.u[4] = f2bf(a1.x); af.u[5] = f2bf(a1.y); af.u[6] = f2bf(a1.z); af.u[7] = f2bf(a1.w);
    #pragma unroll
    for (int ct = 0; ct < 16; ++ct) {
      short8 bv = *(const short8*)&W1b[(ct * 16 + l15) * 128 + s * 32 + quad * 8];
      acc1[ct] = __builtin_amdgcn_mfma_f32_16x16x32_bf16(af.v, bv, acc1[ct], 0, 0, 0);
    }
  }
  // relu + stash hidden (wave-local rows) to LDS as bf16
  #pragma unroll
  for (int ct = 0; ct < 16; ++ct) {
    int col = ct * 16 + l15;
    float bb = b1[col];
    #pragma unroll
    for (int reg = 0; reg < 4; ++reg) {
      int lrow = wv * 16 + quad * 4 + reg;
      Hs[lrow * 264 + col] = f2bf(fmaxf(acc1[ct][reg] + bb, 0.f));
    }
  }
  __syncthreads();

  floatx4 acc2[4];
  #pragma unroll
  for (int i = 0; i < 4; ++i) acc2[i] = (floatx4)0.f;
  #pragma unroll
  for (int s = 0; s < 8; ++s) {
    short8 av = *(const short8*)&Hs[(wv * 16 + l15) * 264 + s * 32 + quad * 8];
    #pragma unroll
    for (int ct = 0; ct < 4; ++ct) {
      short8 bv = *(const short8*)&W2b[(ct * 16 + l15) * 256 + s * 32 + quad * 8];
      acc2[ct] = __builtin_amdgcn_mfma_f32_16x16x32_bf16(av, bv, acc2[ct], 0, 0, 0);
    }
  }
  #pragma unroll
  for (int ct = 0; ct < 4; ++ct) {
    int col = ct * 16 + l15;
    float bb = b2[col];
    #pragma unroll
    for (int reg = 0; reg < 4; ++reg) {
      int node = nb + wv * 16 + quad * 4 + reg;
      if (node < NN) h[(size_t)node * 64 + col] = f2bf(acc2[ct][reg] + bb);
    }
  }
}

// ---------------- scatter-mean aggregation ----------------

__launch_bounds__(256)
__global__ void agg_kernel(const ushort_t* __restrict__ hb, const int* __restrict__ rowptr,
                           const int* __restrict__ csr_src, const float* __restrict__ csr_w,
                           ushort_t* __restrict__ mb) {
  int node = (blockIdx.x * 256 + threadIdx.x) >> 6;
  int lane = threadIdx.x & 63;
  int s = rowptr[node], e = rowptr[node + 1];
  float acc = 0.f;
  for (int p = s; p < e; ++p) {
    int src = csr_src[p];
    float w = csr_w[p];
    acc += w * bf2f(hb[(size_t)src * 64 + lane]);
  }
  float cnt = (float)(e - s);
  mb[(size_t)node * 64 + lane] = f2bf(acc / fmaxf(cnt, 1.f));
}

// ---------------- GRU: MFMA GEMM + in-register gate epilogue ----------------
// A = [m|h] (N x 128), B = Wcb (256 x 128). Wave owns 16 rows x 256 cols ->
// each lane holds r/z/gin/ghn for its (row, col) in acc[j16], acc[4+j16],
// acc[8+j16], acc[12+j16].

__launch_bounds__(256)
__global__ void gru_kernel(const ushort_t* __restrict__ mb, const ushort_t* __restrict__ hb,
                           const ushort_t* __restrict__ Wcb,
                           const float* __restrict__ b_ih, const float* __restrict__ b_hh,
                           ushort_t* __restrict__ hout) {
  int t = threadIdx.x;
  int wv = t >> 6, lane = t & 63;
  int quad = lane >> 4, l15 = lane & 15;
  int nb = blockIdx.x * 64;
  int rowA = min(nb + wv * 16 + l15, NN - 1);

  floatx4 acc[16];
  #pragma unroll
  for (int i = 0; i < 16; ++i) acc[i] = (floatx4)0.f;

  #pragma unroll
  for (int s = 0; s < 4; ++s) {
    int klo = s * 32 + quad * 8;
    const ushort_t* ap = (klo < 64) ? &mb[(size_t)rowA * 64 + klo]
                                    : &hb[(size_t)rowA * 64 + (klo - 64)];
    short8 av = *(const short8*)ap;
    #pragma unroll
    for (int ct = 0; ct < 16; ++ct) {
      short8 bv = *(const short8*)&Wcb[(ct * 16 + l15) * 128 + klo];
      acc[ct] = __builtin_amdgcn_mfma_f32_16x16x32_bf16(av, bv, acc[ct], 0, 0, 0);
    }
  }

  #pragma unroll
  for (int j16 = 0; j16 < 4; ++j16) {
    int j = j16 * 16 + l15;
    float bir = b_ih[j] + b_hh[j];
    float biz = b_ih[64 + j] + b_hh[64 + j];
    float bin_ = b_ih[128 + j];
    float bhn = b_hh[128 + j];
    #pragma unroll
    for (int reg = 0; reg < 4; ++reg) {
      int node = nb + wv * 16 + quad * 4 + reg;
      if (node < NN) {
        float r = sigmoidf_(acc[j16][reg] + bir);
        float z = sigmoidf_(acc[4 + j16][reg] + biz);
        float n = tanhf_fast(acc[8 + j16][reg] + bin_ + r * (acc[12 + j16][reg] + bhn));
        float hp = bf2f(hb[(size_t)node * 64 + j]);
        hout[(size_t)node * 64 + j] = f2bf((1.f - z) * n + z * hp);
      }
    }
  }
}

// ---------------- pooling + head ----------------

__global__ void scatter_kernel(const int* __restrict__ diff, int* __restrict__ flag) {
  int i = blockIdx.x * 256 + threadIdx.x;
  if (i < NDIFF) flag[diff[i]] = 1;
}

__global__ void pool_kernel(const ushort_t* __restrict__ hb, const int* __restrict__ flag,
                            float* __restrict__ pooled) {
  int gw = (blockIdx.x * 256 + threadIdx.x) >> 6;
  int lane = threadIdx.x & 63;
  int nw = (gridDim.x * 256) >> 6;
  float base = 0.f, fl = 0.f, cnt = 0.f;
  for (int n = gw; n < NN; n += nw) {
    float v = bf2f(hb[(size_t)n * 64 + lane]);
    int f = flag[n];
    base += v;
    if (f) { fl += v; cnt += 1.f; }
  }
  atomicAdd(&pooled[lane], base);
  atomicAdd(&pooled[64 + lane], fl);
  if (lane == 0) atomicAdd(&pooled[128], cnt);
}

__global__ void final_kernel(const float* __restrict__ pooled,
                             const float* __restrict__ fc1_w, const float* __restrict__ fc1_b,
                             const float* __restrict__ fc2_w, const float* __restrict__ fc2_b,
                             const float* __restrict__ w_imp, float* __restrict__ out) {
  __shared__ float p[64];
  __shared__ float hid[256];
  __shared__ float o[2];
  int t = threadIdx.x;
  float wpos = softplusf_(w_imp[0]);
  if (t < 64) {
    float num = pooled[t] + wpos * pooled[64 + t];
    float den = (float)NN + wpos * pooled[128];
    p[t] = num / den;
  }
  __syncthreads();
  {
    float a = 0.f;
    for (int k = 0; k < 64; ++k) a += p[k] * fc1_w[t * 64 + k];
    hid[t] = fmaxf(a + fc1_b[t], 0.f);
  }
  __syncthreads();
  if (t < 2) {
    float a = 0.f;
    for (int k = 0; k < 256; ++k) a += hid[k] * fc2_w[t * 256 + k];
    o[t] = a + fc2_b[t];
  }
  __syncthreads();
  if (t == 0) {
    float mx = fmaxf(o[0], o[1]);
    float lse = mx + logf(__expf(o[0] - mx) + __expf(o[1] - mx));
    out[0] = o[0] - lse;
    out[1] = o[1] - lse;
  }
}

// ---------------- launch ----------------

extern "C" void kernel_launch(void* const* d_in, const int* in_sizes, int n_in,
                              void* d_out, int out_size, void* d_ws, size_t ws_size,
                              hipStream_t stream) {
  const float* x        = (const float*)d_in[0];
  const int*   ei       = (const int*)d_in[1];
  const int*   etype    = (const int*)d_in[2];
  const int*   diff_idx = (const int*)d_in[3];
  const float* lin1_w   = (const float*)d_in[4];
  const float* lin1_b   = (const float*)d_in[5];
  const float* lin2_w   = (const float*)d_in[6];
  const float* lin2_b   = (const float*)d_in[7];
  const float* gru_w_ih = (const float*)d_in[8];
  const float* gru_w_hh = (const float*)d_in[9];
  const float* gru_b_ih = (const float*)d_in[10];
  const float* gru_b_hh = (const float*)d_in[11];
  const float* etw      = (const float*)d_in[12];
  const float* fc1_w    = (const float*)d_in[13];
  const float* fc1_b    = (const float*)d_in[14];
  const float* fc2_w    = (const float*)d_in[15];
  const float* fc2_b    = (const float*)d_in[16];
  const float* w_imp    = (const float*)d_in[17];
  float* out = (float*)d_out;

  char* ws = (char*)d_ws;
  size_t off = 0;
  auto alloc = [&](size_t bytes) -> void* {
    void* p = ws + off;
    off += (bytes + 255) & ~(size_t)255;
    return p;
  };
  ushort_t* h0    = (ushort_t*)alloc((size_t)NN * 64 * 2);
  ushort_t* h1    = (ushort_t*)alloc((size_t)NN * 64 * 2);
  ushort_t* mbuf  = (ushort_t*)alloc((size_t)NN * 64 * 2);
  int*   csr_src  = (int*)  alloc((size_t)NE * 4);
  float* csr_w    = (float*)alloc((size_t)NE * 4);
  ushort_t* W1b   = (ushort_t*)alloc(128 * 256 * 2);
  ushort_t* W2b   = (ushort_t*)alloc(256 * 64 * 2);
  ushort_t* Wcb   = (ushort_t*)alloc(128 * 256 * 2);
  int*   rowptr   = (int*)  alloc((size_t)(NN + 1) * 4);
  int*   blockSums = (int*)alloc(128 * 4);
  int*   blockOff  = (int*)alloc(128 * 4);
  int*   zbase    = (int*)  alloc((size_t)(3 * NN + 129) * 4);
  int* deg    = zbase;
  int* cursor = zbase + NN;
  int* flag   = zbase + 2 * NN;
  float* pooled = (float*)(zbase + 3 * NN);

  const int nscan = (NN + 1023) / 1024;  // 98
  const int ngemm = (NN + 63) / 64;      // 1563

  zero_kernel<<<(3 * NN + 129 + 255) / 256, 256, 0, stream>>>(zbase, 3 * NN + 129);
  prep_w_kernel<<<128, 256, 0, stream>>>(lin1_w, lin2_w, gru_w_ih, gru_w_hh, W1b, W2b, Wcb);
  count_kernel<<<(NE + 255) / 256, 256, 0, stream>>>(ei + NE, deg);
  scanA_kernel<<<nscan, 256, 0, stream>>>(deg, rowptr, blockSums);
  scanB_kernel<<<1, 128, 0, stream>>>(blockSums, blockOff, nscan);
  scanC_kernel<<<nscan, 256, 0, stream>>>(rowptr, blockOff);
  fill_kernel<<<(NE + 255) / 256, 256, 0, stream>>>(ei, ei + NE, etype, etw, rowptr, cursor,
                                                    csr_src, csr_w);
  mlp_kernel<<<ngemm, 256, 0, stream>>>(x, W1b, lin1_b, W2b, lin2_b, h0);

  ushort_t* ha = h0;
  ushort_t* hb = h1;
  for (int it = 0; it < 3; ++it) {
    agg_kernel<<<NN / 4, 256, 0, stream>>>(ha, rowptr, csr_src, csr_w, mbuf);
    gru_kernel<<<ngemm, 256, 0, stream>>>(mbuf, ha, Wcb, gru_b_ih, gru_b_hh, hb);
    ushort_t* tmp = ha; ha = hb; hb = tmp;
  }
  scatter_kernel<<<(NDIFF + 255) / 256, 256, 0, stream>>>(diff_idx, flag);
  pool_kernel<<<256, 256, 0, stream>>>(ha, flag, pooled);
  final_kernel<<<1, 256, 0, stream>>>(pooled, fc1_w, fc1_b, fc2_w, fc2_b, w_imp, out);
}

// Round 3
// 769.946 us; speedup vs baseline: 3.4440x; 1.1943x over previous
//
#include <hip/hip_runtime.h>
#include <math.h>

#define NN 100000
#define NE 1200000
#define NDIFF 1000

typedef short short8 __attribute__((ext_vector_type(8)));
typedef float floatx4 __attribute__((ext_vector_type(4)));
typedef unsigned short ushort_t;

__device__ __forceinline__ float softplusf_(float x) {
  return fmaxf(x, 0.f) + logf(1.f + __expf(-fabsf(x)));
}
__device__ __forceinline__ float sigmoidf_(float x) {
  return 1.f / (1.f + __expf(-x));
}
__device__ __forceinline__ float tanhf_fast(float x) {
  float ax = fabsf(x);
  float e = __expf(-2.f * ax);
  float t = (1.f - e) / (1.f + e);
  return x < 0.f ? -t : t;
}
__device__ __forceinline__ ushort_t f2bf(float f) {
  unsigned u = __float_as_uint(f);
  unsigned r = (u + 0x7FFFu + ((u >> 16) & 1u)) >> 16;
  return (ushort_t)r;
}
__device__ __forceinline__ float bf2f(ushort_t s) {
  return __uint_as_float(((unsigned)s) << 16);
}

// ---------------- setup kernels ----------------

__global__ void zero_kernel(int* __restrict__ p, int n) {
  int i = blockIdx.x * 256 + threadIdx.x;
  if (i < n) p[i] = 0;
}

__global__ void count_kernel(const int* __restrict__ dst, int* __restrict__ deg) {
  int e = blockIdx.x * 256 + threadIdx.x;
  if (e < NE) atomicAdd(&deg[dst[e]], 1);
}

// bf16 weights in natural [out][in] layout (B-fragment friendly) + softplus table.
__global__ void prep_w_kernel(const float* __restrict__ lin1_w, const float* __restrict__ lin2_w,
                              const float* __restrict__ w_ih, const float* __restrict__ w_hh,
                              const float* __restrict__ etw,
                              ushort_t* __restrict__ W1b, ushort_t* __restrict__ W2b,
                              ushort_t* __restrict__ Wcb, float* __restrict__ wtab) {
  int i = blockIdx.x * 256 + threadIdx.x;  // 0..32767
  if (i < 8) wtab[i] = softplusf_(etw[i]);
  if (i < 128 * 256) W1b[i] = f2bf(lin1_w[i]);
  if (i < 64 * 256)  W2b[i] = f2bf(lin2_w[i]);
  if (i < 128 * 256) {
    int j = i >> 7, k = i & 127;
    float v;
    if (j < 128)      v = (k < 64) ? w_ih[j * 64 + k] : w_hh[j * 64 + (k - 64)];
    else if (j < 192) v = (k < 64) ? w_ih[j * 64 + k] : 0.f;
    else              v = (k < 64) ? 0.f : w_hh[(j - 64) * 64 + (k - 64)];
    Wcb[i] = f2bf(v);
  }
}

// ---------------- exclusive scan (3 kernels) ----------------

__global__ void scanA_kernel(const int* __restrict__ deg, int* __restrict__ rowptr,
                             int* __restrict__ blockSums) {
  int t = threadIdx.x;
  int base = blockIdx.x * 1024 + t * 4;
  int d0 = (base + 0 < NN) ? deg[base + 0] : 0;
  int d1 = (base + 1 < NN) ? deg[base + 1] : 0;
  int d2 = (base + 2 < NN) ? deg[base + 2] : 0;
  int d3 = (base + 3 < NN) ? deg[base + 3] : 0;
  int s = d0 + d1 + d2 + d3;
  int lane = t & 63;
  int incl = s;
  #pragma unroll
  for (int o = 1; o < 64; o <<= 1) {
    int v = __shfl_up(incl, o, 64);
    if (lane >= o) incl += v;
  }
  __shared__ int wsum[4], woff[4];
  if (lane == 63) wsum[t >> 6] = incl;
  __syncthreads();
  if (t == 0) {
    int r = 0;
    for (int w = 0; w < 4; ++w) { woff[w] = r; r += wsum[w]; }
    blockSums[blockIdx.x] = r;
  }
  __syncthreads();
  int run = woff[t >> 6] + incl - s;
  int dd[4] = {d0, d1, d2, d3};
  #pragma unroll
  for (int q = 0; q < 4; ++q) {
    int idx = base + q;
    if (idx <= NN) rowptr[idx] = run;
    run += dd[q];
  }
}

__global__ void scanB_kernel(const int* __restrict__ blockSums, int* __restrict__ blockOff, int nblk) {
  __shared__ int v[128];
  int t = threadIdx.x;
  int mine = (t < nblk) ? blockSums[t] : 0;
  v[t] = mine;
  __syncthreads();
  for (int o = 1; o < 128; o <<= 1) {
    int add = (t >= o) ? v[t - o] : 0;
    __syncthreads();
    v[t] += add;
    __syncthreads();
  }
  if (t < nblk) blockOff[t] = v[t] - mine;
}

__global__ void scanC_kernel(int* __restrict__ rowptr, int* __restrict__ cursor,
                             const int* __restrict__ blockOff) {
  int t = threadIdx.x;
  int base = blockIdx.x * 1024 + t * 4;
  int add = blockOff[blockIdx.x];
  #pragma unroll
  for (int q = 0; q < 4; ++q) {
    int idx = base + q;
    if (idx <= NN) {
      int v = rowptr[idx] + add;
      rowptr[idx] = v;
      if (idx < NN) cursor[idx] = v;
    }
  }
}

// pack src (17 bits) | etype (3 bits << 17) into one int
__global__ void fill_kernel(const int* __restrict__ src, const int* __restrict__ dst,
                            const int* __restrict__ etype,
                            int* __restrict__ cursor, int* __restrict__ csr) {
  int e = blockIdx.x * 256 + threadIdx.x;
  if (e >= NE) return;
  int d = dst[e];
  int pos = atomicAdd(&cursor[d], 1);
  csr[pos] = src[e] | (etype[e] << 17);
}

// ---------------- fused 2-layer MLP, MFMA bf16 ----------------
// Writes h into the h-slot (offset 64) of interleaved mh[node][128].

__launch_bounds__(256)
__global__ void mlp_kernel(const float* __restrict__ x,
                           const ushort_t* __restrict__ W1b, const float* __restrict__ b1,
                           const ushort_t* __restrict__ W2b, const float* __restrict__ b2,
                           ushort_t* __restrict__ mh) {
  __shared__ ushort_t Hs[64 * 264];
  int t = threadIdx.x;
  int wv = t >> 6, lane = t & 63;
  int quad = lane >> 4, l15 = lane & 15;
  int nb = blockIdx.x * 64;
  int rowA = min(nb + wv * 16 + l15, NN - 1);

  floatx4 acc1[16];
  #pragma unroll
  for (int i = 0; i < 16; ++i) acc1[i] = (floatx4)0.f;

  #pragma unroll
  for (int s = 0; s < 4; ++s) {
    const float* xp = &x[(size_t)rowA * 128 + s * 32 + quad * 8];
    float4 a0 = *(const float4*)xp;
    float4 a1 = *(const float4*)(xp + 4);
    union { short8 v; ushort_t u[8]; } af;
    af.u[0] = f2bf(a0.x); af.u[1] = f2bf(a0.y); af.u[2] = f2bf(a0.z); af.u[3] = f2bf(a0.w);
    af.u[4] = f2bf(a1.x); af.u[5] = f2bf(a1.y); af.u[6] = f2bf(a1.z); af.u[7] = f2bf(a1.w);
    #pragma unroll
    for (int ct = 0; ct < 16; ++ct) {
      short8 bv = *(const short8*)&W1b[(ct * 16 + l15) * 128 + s * 32 + quad * 8];
      acc1[ct] = __builtin_amdgcn_mfma_f32_16x16x32_bf16(af.v, bv, acc1[ct], 0, 0, 0);
    }
  }
  #pragma unroll
  for (int ct = 0; ct < 16; ++ct) {
    int col = ct * 16 + l15;
    float bb = b1[col];
    #pragma unroll
    for (int reg = 0; reg < 4; ++reg) {
      int lrow = wv * 16 + quad * 4 + reg;
      Hs[lrow * 264 + col] = f2bf(fmaxf(acc1[ct][reg] + bb, 0.f));
    }
  }
  __syncthreads();

  floatx4 acc2[4];
  #pragma unroll
  for (int i = 0; i < 4; ++i) acc2[i] = (floatx4)0.f;
  #pragma unroll
  for (int s = 0; s < 8; ++s) {
    short8 av = *(const short8*)&Hs[(wv * 16 + l15) * 264 + s * 32 + quad * 8];
    #pragma unroll
    for (int ct = 0; ct < 4; ++ct) {
      short8 bv = *(const short8*)&W2b[(ct * 16 + l15) * 256 + s * 32 + quad * 8];
      acc2[ct] = __builtin_amdgcn_mfma_f32_16x16x32_bf16(av, bv, acc2[ct], 0, 0, 0);
    }
  }
  #pragma unroll
  for (int ct = 0; ct < 4; ++ct) {
    int col = ct * 16 + l15;
    float bb = b2[col];
    #pragma unroll
    for (int reg = 0; reg < 4; ++reg) {
      int node = nb + wv * 16 + quad * 4 + reg;
      if (node < NN) mh[(size_t)node * 128 + 64 + col] = f2bf(acc2[ct][reg] + bb);
    }
  }
}

// ---------------- scatter-mean aggregation: wave/node, 4-way ILP ----------------

__launch_bounds__(256)
__global__ void agg_kernel(ushort_t* __restrict__ mh, const int* __restrict__ rowptr,
                           const int* __restrict__ csr, const float* __restrict__ wtab) {
  __shared__ float wt[8];
  if (threadIdx.x < 8) wt[threadIdx.x] = wtab[threadIdx.x];
  __syncthreads();
  int node = (blockIdx.x * 256 + threadIdx.x) >> 6;
  int lane = threadIdx.x & 63;
  int s = rowptr[node], e = rowptr[node + 1];
  float acc0 = 0.f, acc1 = 0.f, acc2 = 0.f, acc3 = 0.f;
  int p = s;
  for (; p + 4 <= e; p += 4) {
    int k0 = csr[p], k1 = csr[p + 1], k2 = csr[p + 2], k3 = csr[p + 3];
    float v0 = bf2f(mh[(size_t)(k0 & 0x1FFFF) * 128 + 64 + lane]);
    float v1 = bf2f(mh[(size_t)(k1 & 0x1FFFF) * 128 + 64 + lane]);
    float v2 = bf2f(mh[(size_t)(k2 & 0x1FFFF) * 128 + 64 + lane]);
    float v3 = bf2f(mh[(size_t)(k3 & 0x1FFFF) * 128 + 64 + lane]);
    acc0 += wt[k0 >> 17] * v0;
    acc1 += wt[k1 >> 17] * v1;
    acc2 += wt[k2 >> 17] * v2;
    acc3 += wt[k3 >> 17] * v3;
  }
  for (; p < e; ++p) {
    int k = csr[p];
    acc0 += wt[k >> 17] * bf2f(mh[(size_t)(k & 0x1FFFF) * 128 + 64 + lane]);
  }
  float acc = (acc0 + acc1) + (acc2 + acc3);
  mh[(size_t)node * 128 + lane] = f2bf(acc / fmaxf((float)(e - s), 1.f));
}

// ---------------- GRU: MFMA GEMM, 2 row-tiles/wave, in-register gates ----------------
// A = mh[node][128] ([m|h] contiguous). B = Wcb (256x128). Wave owns 32 rows.

__launch_bounds__(256)
__global__ void gru_kernel(const ushort_t* __restrict__ mhin, const ushort_t* __restrict__ Wcb,
                           const float* __restrict__ b_ih, const float* __restrict__ b_hh,
                           ushort_t* __restrict__ mhout) {
  int t = threadIdx.x;
  int wv = t >> 6, lane = t & 63;
  int quad = lane >> 4, l15 = lane & 15;
  int nb = blockIdx.x * 128;
  int r0 = min(nb + wv * 32 + l15, NN - 1);
  int r1 = min(nb + wv * 32 + 16 + l15, NN - 1);

  floatx4 acc[2][16];
  #pragma unroll
  for (int rt = 0; rt < 2; ++rt)
    #pragma unroll
    for (int i = 0; i < 16; ++i) acc[rt][i] = (floatx4)0.f;

  #pragma unroll
  for (int s = 0; s < 4; ++s) {
    int klo = s * 32 + quad * 8;
    short8 av0 = *(const short8*)&mhin[(size_t)r0 * 128 + klo];
    short8 av1 = *(const short8*)&mhin[(size_t)r1 * 128 + klo];
    #pragma unroll
    for (int ct = 0; ct < 16; ++ct) {
      short8 bv = *(const short8*)&Wcb[(ct * 16 + l15) * 128 + klo];
      acc[0][ct] = __builtin_amdgcn_mfma_f32_16x16x32_bf16(av0, bv, acc[0][ct], 0, 0, 0);
      acc[1][ct] = __builtin_amdgcn_mfma_f32_16x16x32_bf16(av1, bv, acc[1][ct], 0, 0, 0);
    }
  }

  #pragma unroll
  for (int j16 = 0; j16 < 4; ++j16) {
    int j = j16 * 16 + l15;
    float bir = b_ih[j] + b_hh[j];
    float biz = b_ih[64 + j] + b_hh[64 + j];
    float bin_ = b_ih[128 + j];
    float bhn = b_hh[128 + j];
    #pragma unroll
    for (int rt = 0; rt < 2; ++rt) {
      #pragma unroll
      for (int reg = 0; reg < 4; ++reg) {
        int node = nb + wv * 32 + rt * 16 + quad * 4 + reg;
        if (node < NN) {
          float r = sigmoidf_(acc[rt][j16][reg] + bir);
          float z = sigmoidf_(acc[rt][4 + j16][reg] + biz);
          float n = tanhf_fast(acc[rt][8 + j16][reg] + bin_ +
                               r * (acc[rt][12 + j16][reg] + bhn));
          float hp = bf2f(mhin[(size_t)node * 128 + 64 + j]);
          mhout[(size_t)node * 128 + 64 + j] = f2bf((1.f - z) * n + z * hp);
        }
      }
    }
  }
}

// ---------------- pooling + head ----------------

__global__ void scatter_kernel(const int* __restrict__ diff, int* __restrict__ flag) {
  int i = blockIdx.x * 256 + threadIdx.x;
  if (i < NDIFF) flag[diff[i]] = 1;
}

__global__ void pool_kernel(const ushort_t* __restrict__ mh, const int* __restrict__ flag,
                            float* __restrict__ pooled) {
  int gw = (blockIdx.x * 256 + threadIdx.x) >> 6;
  int lane = threadIdx.x & 63;
  int nw = (gridDim.x * 256) >> 6;
  float base = 0.f, fl = 0.f, cnt = 0.f;
  for (int n = gw; n < NN; n += nw) {
    float v = bf2f(mh[(size_t)n * 128 + 64 + lane]);
    int f = flag[n];
    base += v;
    if (f) { fl += v; cnt += 1.f; }
  }
  atomicAdd(&pooled[lane], base);
  atomicAdd(&pooled[64 + lane], fl);
  if (lane == 0) atomicAdd(&pooled[128], cnt);
}

__global__ void final_kernel(const float* __restrict__ pooled,
                             const float* __restrict__ fc1_w, const float* __restrict__ fc1_b,
                             const float* __restrict__ fc2_w, const float* __restrict__ fc2_b,
                             const float* __restrict__ w_imp, float* __restrict__ out) {
  __shared__ float p[64];
  __shared__ float hid[256];
  __shared__ float o[2];
  int t = threadIdx.x;
  float wpos = softplusf_(w_imp[0]);
  if (t < 64) {
    float num = pooled[t] + wpos * pooled[64 + t];
    float den = (float)NN + wpos * pooled[128];
    p[t] = num / den;
  }
  __syncthreads();
  {
    float a = 0.f;
    for (int k = 0; k < 64; ++k) a += p[k] * fc1_w[t * 64 + k];
    hid[t] = fmaxf(a + fc1_b[t], 0.f);
  }
  __syncthreads();
  if (t < 2) {
    float a = 0.f;
    for (int k = 0; k < 256; ++k) a += hid[k] * fc2_w[t * 256 + k];
    o[t] = a + fc2_b[t];
  }
  __syncthreads();
  if (t == 0) {
    float mx = fmaxf(o[0], o[1]);
    float lse = mx + logf(__expf(o[0] - mx) + __expf(o[1] - mx));
    out[0] = o[0] - lse;
    out[1] = o[1] - lse;
  }
}

// ---------------- launch ----------------

extern "C" void kernel_launch(void* const* d_in, const int* in_sizes, int n_in,
                              void* d_out, int out_size, void* d_ws, size_t ws_size,
                              hipStream_t stream) {
  const float* x        = (const float*)d_in[0];
  const int*   ei       = (const int*)d_in[1];
  const int*   etype    = (const int*)d_in[2];
  const int*   diff_idx = (const int*)d_in[3];
  const float* lin1_w   = (const float*)d_in[4];
  const float* lin1_b   = (const float*)d_in[5];
  const float* lin2_w   = (const float*)d_in[6];
  const float* lin2_b   = (const float*)d_in[7];
  const float* gru_w_ih = (const float*)d_in[8];
  const float* gru_w_hh = (const float*)d_in[9];
  const float* gru_b_ih = (const float*)d_in[10];
  const float* gru_b_hh = (const float*)d_in[11];
  const float* etw      = (const float*)d_in[12];
  const float* fc1_w    = (const float*)d_in[13];
  const float* fc1_b    = (const float*)d_in[14];
  const float* fc2_w    = (const float*)d_in[15];
  const float* fc2_b    = (const float*)d_in[16];
  const float* w_imp    = (const float*)d_in[17];
  float* out = (float*)d_out;

  char* ws = (char*)d_ws;
  size_t off = 0;
  auto alloc = [&](size_t bytes) -> void* {
    void* p = ws + off;
    off += (bytes + 255) & ~(size_t)255;
    return p;
  };
  ushort_t* mh0   = (ushort_t*)alloc((size_t)NN * 128 * 2);
  ushort_t* mh1   = (ushort_t*)alloc((size_t)NN * 128 * 2);
  int*   csr      = (int*)  alloc((size_t)NE * 4);
  ushort_t* W1b   = (ushort_t*)alloc(128 * 256 * 2);
  ushort_t* W2b   = (ushort_t*)alloc(256 * 64 * 2);
  ushort_t* Wcb   = (ushort_t*)alloc(128 * 256 * 2);
  float* wtab     = (float*)alloc(8 * 4);
  int*   rowptr   = (int*)  alloc((size_t)(NN + 1) * 4);
  int*   cursor   = (int*)  alloc((size_t)NN * 4);
  int*   blockSums = (int*)alloc(128 * 4);
  int*   blockOff  = (int*)alloc(128 * 4);
  int*   zbase    = (int*)  alloc((size_t)(2 * NN + 129) * 4);
  int* deg    = zbase;
  int* flag   = zbase + NN;
  float* pooled = (float*)(zbase + 2 * NN);

  const int nscan = (NN + 1023) / 1024;  // 98
  const int nmlp  = (NN + 63) / 64;      // 1563
  const int ngru  = (NN + 127) / 128;    // 782

  zero_kernel<<<(2 * NN + 129 + 255) / 256, 256, 0, stream>>>(zbase, 2 * NN + 129);
  prep_w_kernel<<<128, 256, 0, stream>>>(lin1_w, lin2_w, gru_w_ih, gru_w_hh, etw,
                                         W1b, W2b, Wcb, wtab);
  count_kernel<<<(NE + 255) / 256, 256, 0, stream>>>(ei + NE, deg);
  scanA_kernel<<<nscan, 256, 0, stream>>>(deg, rowptr, blockSums);
  scanB_kernel<<<1, 128, 0, stream>>>(blockSums, blockOff, nscan);
  scanC_kernel<<<nscan, 256, 0, stream>>>(rowptr, cursor, blockOff);
  fill_kernel<<<(NE + 255) / 256, 256, 0, stream>>>(ei, ei + NE, etype, cursor, csr);
  mlp_kernel<<<nmlp, 256, 0, stream>>>(x, W1b, lin1_b, W2b, lin2_b, mh0);

  ushort_t* ha = mh0;
  ushort_t* hb = mh1;
  for (int it = 0; it < 3; ++it) {
    agg_kernel<<<NN / 4, 256, 0, stream>>>(ha, rowptr, csr, wtab);
    gru_kernel<<<ngru, 256, 0, stream>>>(ha, Wcb, gru_b_ih, gru_b_hh, hb);
    ushort_t* tmp = ha; ha = hb; hb = tmp;
  }
  scatter_kernel<<<(NDIFF + 255) / 256, 256, 0, stream>>>(diff_idx, flag);
  pool_kernel<<<256, 256, 0, stream>>>(ha, flag, pooled);
  final_kernel<<<1, 256, 0, stream>>>(pooled, fc1_w, fc1_b, fc2_w, fc2_b, w_imp, out);
}

// Round 4
// 703.427 us; speedup vs baseline: 3.7696x; 1.0946x over previous
//
#include <hip/hip_runtime.h>
#include <math.h>

#define NN 100000
#define NE 1200000
#define NDIFF 1000

typedef short short8 __attribute__((ext_vector_type(8)));
typedef float floatx4 __attribute__((ext_vector_type(4)));
typedef unsigned short ushort_t;

__device__ __forceinline__ float softplusf_(float x) {
  return fmaxf(x, 0.f) + logf(1.f + __expf(-fabsf(x)));
}
__device__ __forceinline__ float sigmoidf_(float x) {
  return 1.f / (1.f + __expf(-x));
}
__device__ __forceinline__ float tanhf_fast(float x) {
  float ax = fabsf(x);
  float e = __expf(-2.f * ax);
  float t = (1.f - e) / (1.f + e);
  return x < 0.f ? -t : t;
}
__device__ __forceinline__ ushort_t f2bf(float f) {
  unsigned u = __float_as_uint(f);
  unsigned r = (u + 0x7FFFu + ((u >> 16) & 1u)) >> 16;
  return (ushort_t)r;
}
__device__ __forceinline__ float bf2f(ushort_t s) {
  return __uint_as_float(((unsigned)s) << 16);
}

// ---------------- setup kernels ----------------

__global__ void zero_kernel(int* __restrict__ p, int n) {
  int i = blockIdx.x * 256 + threadIdx.x;
  if (i < n) p[i] = 0;
}

__global__ void count_kernel(const int* __restrict__ dst, int* __restrict__ deg) {
  int e = blockIdx.x * 256 + threadIdx.x;
  if (e < NE) atomicAdd(&deg[dst[e]], 1);
}

// bf16 weights in natural [out][in] layout (B-fragment friendly) + softplus table.
__global__ void prep_w_kernel(const float* __restrict__ lin1_w, const float* __restrict__ lin2_w,
                              const float* __restrict__ w_ih, const float* __restrict__ w_hh,
                              const float* __restrict__ etw,
                              ushort_t* __restrict__ W1b, ushort_t* __restrict__ W2b,
                              ushort_t* __restrict__ Wcb, float* __restrict__ wtab) {
  int i = blockIdx.x * 256 + threadIdx.x;  // 0..32767
  if (i < 8) wtab[i] = softplusf_(etw[i]);
  if (i < 128 * 256) W1b[i] = f2bf(lin1_w[i]);
  if (i < 64 * 256)  W2b[i] = f2bf(lin2_w[i]);
  if (i < 128 * 256) {
    int j = i >> 7, k = i & 127;
    float v;
    if (j < 128)      v = (k < 64) ? w_ih[j * 64 + k] : w_hh[j * 64 + (k - 64)];
    else if (j < 192) v = (k < 64) ? w_ih[j * 64 + k] : 0.f;
    else              v = (k < 64) ? 0.f : w_hh[(j - 64) * 64 + (k - 64)];
    Wcb[i] = f2bf(v);
  }
}

// ---------------- exclusive scan (3 kernels) ----------------

__global__ void scanA_kernel(const int* __restrict__ deg, int* __restrict__ rowptr,
                             int* __restrict__ blockSums) {
  int t = threadIdx.x;
  int base = blockIdx.x * 1024 + t * 4;
  int d0 = (base + 0 < NN) ? deg[base + 0] : 0;
  int d1 = (base + 1 < NN) ? deg[base + 1] : 0;
  int d2 = (base + 2 < NN) ? deg[base + 2] : 0;
  int d3 = (base + 3 < NN) ? deg[base + 3] : 0;
  int s = d0 + d1 + d2 + d3;
  int lane = t & 63;
  int incl = s;
  #pragma unroll
  for (int o = 1; o < 64; o <<= 1) {
    int v = __shfl_up(incl, o, 64);
    if (lane >= o) incl += v;
  }
  __shared__ int wsum[4], woff[4];
  if (lane == 63) wsum[t >> 6] = incl;
  __syncthreads();
  if (t == 0) {
    int r = 0;
    for (int w = 0; w < 4; ++w) { woff[w] = r; r += wsum[w]; }
    blockSums[blockIdx.x] = r;
  }
  __syncthreads();
  int run = woff[t >> 6] + incl - s;
  int dd[4] = {d0, d1, d2, d3};
  #pragma unroll
  for (int q = 0; q < 4; ++q) {
    int idx = base + q;
    if (idx <= NN) rowptr[idx] = run;
    run += dd[q];
  }
}

__global__ void scanB_kernel(const int* __restrict__ blockSums, int* __restrict__ blockOff, int nblk) {
  __shared__ int v[128];
  int t = threadIdx.x;
  int mine = (t < nblk) ? blockSums[t] : 0;
  v[t] = mine;
  __syncthreads();
  for (int o = 1; o < 128; o <<= 1) {
    int add = (t >= o) ? v[t - o] : 0;
    __syncthreads();
    v[t] += add;
    __syncthreads();
  }
  if (t < nblk) blockOff[t] = v[t] - mine;
}

__global__ void scanC_kernel(int* __restrict__ rowptr, int* __restrict__ cursor,
                             const int* __restrict__ blockOff) {
  int t = threadIdx.x;
  int base = blockIdx.x * 1024 + t * 4;
  int add = blockOff[blockIdx.x];
  #pragma unroll
  for (int q = 0; q < 4; ++q) {
    int idx = base + q;
    if (idx <= NN) {
      int v = rowptr[idx] + add;
      rowptr[idx] = v;
      if (idx < NN) cursor[idx] = v;
    }
  }
}

// pack src (17 bits) | etype (3 bits << 17) into one int
__global__ void fill_kernel(const int* __restrict__ src, const int* __restrict__ dst,
                            const int* __restrict__ etype,
                            int* __restrict__ cursor, int* __restrict__ csr) {
  int e = blockIdx.x * 256 + threadIdx.x;
  if (e >= NE) return;
  int d = dst[e];
  int pos = atomicAdd(&cursor[d], 1);
  csr[pos] = src[e] | (etype[e] << 17);
}

// ---------------- fused 2-layer MLP, MFMA bf16, occupancy-tuned ----------------
// Block = 32 rows, 4 waves. L1: wave w owns cols w*64..w*64+63, both row-tiles
// (acc 8 tiles = 32 f32). L2: wave w owns row-tile (w&1), col-tiles
// {(w>>1)*2, (w>>1)*2+1} (acc 8 f32). 32*3125 == 100000 exactly (no guards).

__launch_bounds__(256)
__global__ void mlp_kernel(const float* __restrict__ x,
                           const ushort_t* __restrict__ W1b, const float* __restrict__ b1,
                           const ushort_t* __restrict__ W2b, const float* __restrict__ b2,
                           ushort_t* __restrict__ mh) {
  __shared__ ushort_t Hs[32 * 264];
  int t = threadIdx.x;
  int wv = t >> 6, lane = t & 63;
  int quad = lane >> 4, l15 = lane & 15;
  int nb = blockIdx.x * 32;

  floatx4 acc1[2][4];
  #pragma unroll
  for (int rt = 0; rt < 2; ++rt)
    #pragma unroll
    for (int ct = 0; ct < 4; ++ct) acc1[rt][ct] = (floatx4)0.f;

  #pragma unroll
  for (int s = 0; s < 4; ++s) {
    int klo = s * 32 + quad * 8;
    short8 av[2];
    #pragma unroll
    for (int rt = 0; rt < 2; ++rt) {
      const float* xp = &x[(size_t)(nb + rt * 16 + l15) * 128 + klo];
      float4 a0 = *(const float4*)xp;
      float4 a1 = *(const float4*)(xp + 4);
      union { short8 v; ushort_t u[8]; } af;
      af.u[0] = f2bf(a0.x); af.u[1] = f2bf(a0.y); af.u[2] = f2bf(a0.z); af.u[3] = f2bf(a0.w);
      af.u[4] = f2bf(a1.x); af.u[5] = f2bf(a1.y); af.u[6] = f2bf(a1.z); af.u[7] = f2bf(a1.w);
      av[rt] = af.v;
    }
    #pragma unroll
    for (int ct = 0; ct < 4; ++ct) {
      short8 bv = *(const short8*)&W1b[((wv * 4 + ct) * 16 + l15) * 128 + klo];
      acc1[0][ct] = __builtin_amdgcn_mfma_f32_16x16x32_bf16(av[0], bv, acc1[0][ct], 0, 0, 0);
      acc1[1][ct] = __builtin_amdgcn_mfma_f32_16x16x32_bf16(av[1], bv, acc1[1][ct], 0, 0, 0);
    }
  }
  #pragma unroll
  for (int ct = 0; ct < 4; ++ct) {
    int col = (wv * 4 + ct) * 16 + l15;
    float bb = b1[col];
    #pragma unroll
    for (int rt = 0; rt < 2; ++rt)
      #pragma unroll
      for (int reg = 0; reg < 4; ++reg)
        Hs[(rt * 16 + quad * 4 + reg) * 264 + col] = f2bf(fmaxf(acc1[rt][ct][reg] + bb, 0.f));
  }
  __syncthreads();

  int rt2 = wv & 1;
  int tcb = (wv >> 1) * 2;
  floatx4 acc2[2];
  acc2[0] = (floatx4)0.f;
  acc2[1] = (floatx4)0.f;
  #pragma unroll
  for (int s = 0; s < 8; ++s) {
    short8 av = *(const short8*)&Hs[(rt2 * 16 + l15) * 264 + s * 32 + quad * 8];
    #pragma unroll
    for (int c2 = 0; c2 < 2; ++c2) {
      short8 bv = *(const short8*)&W2b[((tcb + c2) * 16 + l15) * 256 + s * 32 + quad * 8];
      acc2[c2] = __builtin_amdgcn_mfma_f32_16x16x32_bf16(av, bv, acc2[c2], 0, 0, 0);
    }
  }
  #pragma unroll
  for (int c2 = 0; c2 < 2; ++c2) {
    int col = (tcb + c2) * 16 + l15;
    float bb = b2[col];
    #pragma unroll
    for (int reg = 0; reg < 4; ++reg) {
      int node = nb + rt2 * 16 + quad * 4 + reg;
      mh[(size_t)node * 128 + 64 + col] = f2bf(acc2[c2][reg] + bb);
    }
  }
}

// ---------------- scatter-mean aggregation: wave/node, 8-way ILP ----------------

__launch_bounds__(256)
__global__ void agg_kernel(ushort_t* __restrict__ mh, const int* __restrict__ rowptr,
                           const int* __restrict__ csr, const float* __restrict__ wtab) {
  __shared__ float wt[8];
  if (threadIdx.x < 8) wt[threadIdx.x] = wtab[threadIdx.x];
  __syncthreads();
  int node = (blockIdx.x * 256 + threadIdx.x) >> 6;
  int lane = threadIdx.x & 63;
  int s = rowptr[node], e = rowptr[node + 1];
  float acc0 = 0.f, acc1 = 0.f, acc2 = 0.f, acc3 = 0.f;
  float acc4 = 0.f, acc5 = 0.f, acc6 = 0.f, acc7 = 0.f;
  int p = s;
  for (; p + 8 <= e; p += 8) {
    int k0 = csr[p], k1 = csr[p + 1], k2 = csr[p + 2], k3 = csr[p + 3];
    int k4 = csr[p + 4], k5 = csr[p + 5], k6 = csr[p + 6], k7 = csr[p + 7];
    float v0 = bf2f(mh[(size_t)(k0 & 0x1FFFF) * 128 + 64 + lane]);
    float v1 = bf2f(mh[(size_t)(k1 & 0x1FFFF) * 128 + 64 + lane]);
    float v2 = bf2f(mh[(size_t)(k2 & 0x1FFFF) * 128 + 64 + lane]);
    float v3 = bf2f(mh[(size_t)(k3 & 0x1FFFF) * 128 + 64 + lane]);
    float v4 = bf2f(mh[(size_t)(k4 & 0x1FFFF) * 128 + 64 + lane]);
    float v5 = bf2f(mh[(size_t)(k5 & 0x1FFFF) * 128 + 64 + lane]);
    float v6 = bf2f(mh[(size_t)(k6 & 0x1FFFF) * 128 + 64 + lane]);
    float v7 = bf2f(mh[(size_t)(k7 & 0x1FFFF) * 128 + 64 + lane]);
    acc0 += wt[k0 >> 17] * v0;
    acc1 += wt[k1 >> 17] * v1;
    acc2 += wt[k2 >> 17] * v2;
    acc3 += wt[k3 >> 17] * v3;
    acc4 += wt[k4 >> 17] * v4;
    acc5 += wt[k5 >> 17] * v5;
    acc6 += wt[k6 >> 17] * v6;
    acc7 += wt[k7 >> 17] * v7;
  }
  for (; p + 4 <= e; p += 4) {
    int k0 = csr[p], k1 = csr[p + 1], k2 = csr[p + 2], k3 = csr[p + 3];
    float v0 = bf2f(mh[(size_t)(k0 & 0x1FFFF) * 128 + 64 + lane]);
    float v1 = bf2f(mh[(size_t)(k1 & 0x1FFFF) * 128 + 64 + lane]);
    float v2 = bf2f(mh[(size_t)(k2 & 0x1FFFF) * 128 + 64 + lane]);
    float v3 = bf2f(mh[(size_t)(k3 & 0x1FFFF) * 128 + 64 + lane]);
    acc0 += wt[k0 >> 17] * v0;
    acc1 += wt[k1 >> 17] * v1;
    acc2 += wt[k2 >> 17] * v2;
    acc3 += wt[k3 >> 17] * v3;
  }
  for (; p < e; ++p) {
    int k = csr[p];
    acc0 += wt[k >> 17] * bf2f(mh[(size_t)(k & 0x1FFFF) * 128 + 64 + lane]);
  }
  float acc = ((acc0 + acc1) + (acc2 + acc3)) + ((acc4 + acc5) + (acc6 + acc7));
  mh[(size_t)node * 128 + lane] = f2bf(acc / fmaxf((float)(e - s), 1.f));
}

// ---------------- GRU: MFMA GEMM, column-half/wave (32 AGPR), in-register gates ----
// Block = 32 rows, 4 waves. Wave w: row-tile rt = w&1, col-half ch = w>>1
// (j16 in {2ch, 2ch+1}); computes all 4 gates for those cols: tiles g*4+j16.

__launch_bounds__(256)
__global__ void gru_kernel(const ushort_t* __restrict__ mhin, const ushort_t* __restrict__ Wcb,
                           const float* __restrict__ b_ih, const float* __restrict__ b_hh,
                           ushort_t* __restrict__ mhout) {
  int t = threadIdx.x;
  int wv = t >> 6, lane = t & 63;
  int quad = lane >> 4, l15 = lane & 15;
  int nb = blockIdx.x * 32;
  int rt = wv & 1, ch = wv >> 1;
  int rowA = nb + rt * 16 + l15;

  floatx4 acc[2][4];  // [c2][gate]
  #pragma unroll
  for (int c2 = 0; c2 < 2; ++c2)
    #pragma unroll
    for (int g = 0; g < 4; ++g) acc[c2][g] = (floatx4)0.f;

  #pragma unroll
  for (int s = 0; s < 4; ++s) {
    int klo = s * 32 + quad * 8;
    short8 av = *(const short8*)&mhin[(size_t)rowA * 128 + klo];
    #pragma unroll
    for (int g = 0; g < 4; ++g)
      #pragma unroll
      for (int c2 = 0; c2 < 2; ++c2) {
        short8 bv = *(const short8*)&Wcb[((g * 4 + 2 * ch + c2) * 16 + l15) * 128 + klo];
        acc[c2][g] = __builtin_amdgcn_mfma_f32_16x16x32_bf16(av, bv, acc[c2][g], 0, 0, 0);
      }
  }

  #pragma unroll
  for (int c2 = 0; c2 < 2; ++c2) {
    int j = (2 * ch + c2) * 16 + l15;
    float bir = b_ih[j] + b_hh[j];
    float biz = b_ih[64 + j] + b_hh[64 + j];
    float bin_ = b_ih[128 + j];
    float bhn = b_hh[128 + j];
    #pragma unroll
    for (int reg = 0; reg < 4; ++reg) {
      int node = nb + rt * 16 + quad * 4 + reg;
      float r = sigmoidf_(acc[c2][0][reg] + bir);
      float z = sigmoidf_(acc[c2][1][reg] + biz);
      float n = tanhf_fast(acc[c2][2][reg] + bin_ + r * (acc[c2][3][reg] + bhn));
      float hp = bf2f(mhin[(size_t)node * 128 + 64 + j]);
      mhout[(size_t)node * 128 + 64 + j] = f2bf((1.f - z) * n + z * hp);
    }
  }
}

// ---------------- pooling + head ----------------

__global__ void scatter_kernel(const int* __restrict__ diff, int* __restrict__ flag) {
  int i = blockIdx.x * 256 + threadIdx.x;
  if (i < NDIFF) flag[diff[i]] = 1;
}

// 1024 waves; wave gw handles a contiguous chunk, 4-way unrolled.
__global__ void pool_kernel(const ushort_t* __restrict__ mh, const int* __restrict__ flag,
                            float* __restrict__ pooled) {
  int gw = (blockIdx.x * 256 + threadIdx.x) >> 6;
  int lane = threadIdx.x & 63;
  const int chunk = (NN + 1023) / 1024;  // 98
  int n0 = gw * chunk;
  int n1 = min(n0 + chunk, NN);
  float base = 0.f, fl = 0.f, cnt = 0.f;
  int n = n0;
  for (; n + 4 <= n1; n += 4) {
    float v0 = bf2f(mh[(size_t)(n + 0) * 128 + 64 + lane]);
    float v1 = bf2f(mh[(size_t)(n + 1) * 128 + 64 + lane]);
    float v2 = bf2f(mh[(size_t)(n + 2) * 128 + 64 + lane]);
    float v3 = bf2f(mh[(size_t)(n + 3) * 128 + 64 + lane]);
    int f0 = flag[n + 0], f1 = flag[n + 1], f2 = flag[n + 2], f3 = flag[n + 3];
    base += (v0 + v1) + (v2 + v3);
    if (f0) { fl += v0; cnt += 1.f; }
    if (f1) { fl += v1; cnt += 1.f; }
    if (f2) { fl += v2; cnt += 1.f; }
    if (f3) { fl += v3; cnt += 1.f; }
  }
  for (; n < n1; ++n) {
    float v = bf2f(mh[(size_t)n * 128 + 64 + lane]);
    base += v;
    if (flag[n]) { fl += v; cnt += 1.f; }
  }
  atomicAdd(&pooled[lane], base);
  atomicAdd(&pooled[64 + lane], fl);
  if (lane == 0) atomicAdd(&pooled[128], cnt);
}

__global__ void final_kernel(const float* __restrict__ pooled,
                             const float* __restrict__ fc1_w, const float* __restrict__ fc1_b,
                             const float* __restrict__ fc2_w, const float* __restrict__ fc2_b,
                             const float* __restrict__ w_imp, float* __restrict__ out) {
  __shared__ float p[64];
  __shared__ float hid[256];
  __shared__ float o[2];
  int t = threadIdx.x;
  float wpos = softplusf_(w_imp[0]);
  if (t < 64) {
    float num = pooled[t] + wpos * pooled[64 + t];
    float den = (float)NN + wpos * pooled[128];
    p[t] = num / den;
  }
  __syncthreads();
  {
    float a = 0.f;
    for (int k = 0; k < 64; ++k) a += p[k] * fc1_w[t * 64 + k];
    hid[t] = fmaxf(a + fc1_b[t], 0.f);
  }
  __syncthreads();
  if (t < 2) {
    float a = 0.f;
    for (int k = 0; k < 256; ++k) a += hid[k] * fc2_w[t * 256 + k];
    o[t] = a + fc2_b[t];
  }
  __syncthreads();
  if (t == 0) {
    float mx = fmaxf(o[0], o[1]);
    float lse = mx + logf(__expf(o[0] - mx) + __expf(o[1] - mx));
    out[0] = o[0] - lse;
    out[1] = o[1] - lse;
  }
}

// ---------------- launch ----------------

extern "C" void kernel_launch(void* const* d_in, const int* in_sizes, int n_in,
                              void* d_out, int out_size, void* d_ws, size_t ws_size,
                              hipStream_t stream) {
  const float* x        = (const float*)d_in[0];
  const int*   ei       = (const int*)d_in[1];
  const int*   etype    = (const int*)d_in[2];
  const int*   diff_idx = (const int*)d_in[3];
  const float* lin1_w   = (const float*)d_in[4];
  const float* lin1_b   = (const float*)d_in[5];
  const float* lin2_w   = (const float*)d_in[6];
  const float* lin2_b   = (const float*)d_in[7];
  const float* gru_w_ih = (const float*)d_in[8];
  const float* gru_w_hh = (const float*)d_in[9];
  const float* gru_b_ih = (const float*)d_in[10];
  const float* gru_b_hh = (const float*)d_in[11];
  const float* etw      = (const float*)d_in[12];
  const float* fc1_w    = (const float*)d_in[13];
  const float* fc1_b    = (const float*)d_in[14];
  const float* fc2_w    = (const float*)d_in[15];
  const float* fc2_b    = (const float*)d_in[16];
  const float* w_imp    = (const float*)d_in[17];
  float* out = (float*)d_out;

  char* ws = (char*)d_ws;
  size_t off = 0;
  auto alloc = [&](size_t bytes) -> void* {
    void* p = ws + off;
    off += (bytes + 255) & ~(size_t)255;
    return p;
  };
  ushort_t* mh0   = (ushort_t*)alloc((size_t)NN * 128 * 2);
  ushort_t* mh1   = (ushort_t*)alloc((size_t)NN * 128 * 2);
  int*   csr      = (int*)  alloc((size_t)NE * 4);
  ushort_t* W1b   = (ushort_t*)alloc(128 * 256 * 2);
  ushort_t* W2b   = (ushort_t*)alloc(256 * 64 * 2);
  ushort_t* Wcb   = (ushort_t*)alloc(128 * 256 * 2);
  float* wtab     = (float*)alloc(8 * 4);
  int*   rowptr   = (int*)  alloc((size_t)(NN + 1) * 4);
  int*   cursor   = (int*)  alloc((size_t)NN * 4);
  int*   blockSums = (int*)alloc(128 * 4);
  int*   blockOff  = (int*)alloc(128 * 4);
  int*   zbase    = (int*)  alloc((size_t)(2 * NN + 129) * 4);
  int* deg    = zbase;
  int* flag   = zbase + NN;
  float* pooled = (float*)(zbase + 2 * NN);

  const int nscan = (NN + 1023) / 1024;  // 98
  const int ngemm = NN / 32;             // 3125 (exact)

  zero_kernel<<<(2 * NN + 129 + 255) / 256, 256, 0, stream>>>(zbase, 2 * NN + 129);
  prep_w_kernel<<<128, 256, 0, stream>>>(lin1_w, lin2_w, gru_w_ih, gru_w_hh, etw,
                                         W1b, W2b, Wcb, wtab);
  count_kernel<<<(NE + 255) / 256, 256, 0, stream>>>(ei + NE, deg);
  scanA_kernel<<<nscan, 256, 0, stream>>>(deg, rowptr, blockSums);
  scanB_kernel<<<1, 128, 0, stream>>>(blockSums, blockOff, nscan);
  scanC_kernel<<<nscan, 256, 0, stream>>>(rowptr, cursor, blockOff);
  fill_kernel<<<(NE + 255) / 256, 256, 0, stream>>>(ei, ei + NE, etype, cursor, csr);
  mlp_kernel<<<ngemm, 256, 0, stream>>>(x, W1b, lin1_b, W2b, lin2_b, mh0);

  ushort_t* ha = mh0;
  ushort_t* hb = mh1;
  for (int it = 0; it < 3; ++it) {
    agg_kernel<<<NN / 4, 256, 0, stream>>>(ha, rowptr, csr, wtab);
    gru_kernel<<<ngemm, 256, 0, stream>>>(ha, Wcb, gru_b_ih, gru_b_hh, hb);
    ushort_t* tmp = ha; ha = hb; hb = tmp;
  }
  scatter_kernel<<<(NDIFF + 255) / 256, 256, 0, stream>>>(diff_idx, flag);
  pool_kernel<<<256, 256, 0, stream>>>(ha, flag, pooled);
  final_kernel<<<1, 256, 0, stream>>>(pooled, fc1_w, fc1_b, fc2_w, fc2_b, w_imp, out);
}

// Round 5
// 535.135 us; speedup vs baseline: 4.9551x; 1.3145x over previous
//
#include <hip/hip_runtime.h>
#include <math.h>

#define NN 100000
#define NE 1200000
#define NDIFF 1000

typedef short short8 __attribute__((ext_vector_type(8)));
typedef float floatx4 __attribute__((ext_vector_type(4)));
typedef unsigned short ushort_t;

__device__ __forceinline__ float softplusf_(float x) {
  return fmaxf(x, 0.f) + logf(1.f + __expf(-fabsf(x)));
}
__device__ __forceinline__ float sigmoidf_(float x) {
  return 1.f / (1.f + __expf(-x));
}
__device__ __forceinline__ float tanhf_fast(float x) {
  float ax = fabsf(x);
  float e = __expf(-2.f * ax);
  float t = (1.f - e) / (1.f + e);
  return x < 0.f ? -t : t;
}
__device__ __forceinline__ ushort_t f2bf(float f) {
  unsigned u = __float_as_uint(f);
  unsigned r = (u + 0x7FFFu + ((u >> 16) & 1u)) >> 16;
  return (ushort_t)r;
}
__device__ __forceinline__ float bf2f(ushort_t s) {
  return __uint_as_float(((unsigned)s) << 16);
}

// ---------------- setup kernels ----------------

__global__ void zero_kernel(int* __restrict__ p, int n) {
  int i = blockIdx.x * 256 + threadIdx.x;
  if (i < n) p[i] = 0;
}

__global__ void count_kernel(const int* __restrict__ dst, int* __restrict__ deg) {
  int e = blockIdx.x * 256 + threadIdx.x;
  if (e < NE) atomicAdd(&deg[dst[e]], 1);
}

// Fragment-major bf16 weights: for MFMA 16x16x32, B-fragment of (s,ct) is
// 64 lanes x 8 bf16 stored contiguously (1KB). lane = quad*16+l15;
// element j: W[col=ct*16+l15][k=s*32+quad*8+j].
//  W1s: 4 s x 16 ct (lin1_w, 256x128)
//  W2s: 8 s x 4  ct (lin2_w, 64x256)
//  Wcs: 4 s x 16 ct (combined GRU 256x128: rows r(64),z(64),gi_n(64),gh_n(64),
//       input [m(64)|h(64)])
__global__ void prep_w_kernel(const float* __restrict__ lin1_w, const float* __restrict__ lin2_w,
                              const float* __restrict__ w_ih, const float* __restrict__ w_hh,
                              const float* __restrict__ etw,
                              ushort_t* __restrict__ W1s, ushort_t* __restrict__ W2s,
                              ushort_t* __restrict__ Wcs, float* __restrict__ wtab) {
  int i = blockIdx.x * 256 + threadIdx.x;  // 0..81919
  if (i < 8) wtab[i] = softplusf_(etw[i]);
  if (i < 32768) {
    int fi = i >> 9, lane = (i >> 3) & 63, j = i & 7;
    int s = fi >> 4, ct = fi & 15;
    int quad = lane >> 4, l15 = lane & 15;
    int col = ct * 16 + l15, k = s * 32 + quad * 8 + j;
    W1s[i] = f2bf(lin1_w[col * 128 + k]);
  } else if (i < 49152) {
    int i2 = i - 32768;
    int fi = i2 >> 9, lane = (i2 >> 3) & 63, j = i2 & 7;
    int s = fi >> 2, ct = fi & 3;
    int quad = lane >> 4, l15 = lane & 15;
    int col = ct * 16 + l15, k = s * 32 + quad * 8 + j;
    W2s[i2] = f2bf(lin2_w[col * 256 + k]);
  } else {
    int i3 = i - 49152;
    int fi = i3 >> 9, lane = (i3 >> 3) & 63, j = i3 & 7;
    int s = fi >> 4, ct = fi & 15;
    int quad = lane >> 4, l15 = lane & 15;
    int jj = ct * 16 + l15, k = s * 32 + quad * 8 + j;
    float v;
    if (jj < 128)      v = (k < 64) ? w_ih[jj * 64 + k] : w_hh[jj * 64 + (k - 64)];
    else if (jj < 192) v = (k < 64) ? w_ih[jj * 64 + k] : 0.f;
    else               v = (k < 64) ? 0.f : w_hh[(jj - 64) * 64 + (k - 64)];
    Wcs[i3] = f2bf(v);
  }
}

// ---------------- exclusive scan (3 kernels) ----------------

__global__ void scanA_kernel(const int* __restrict__ deg, int* __restrict__ rowptr,
                             int* __restrict__ blockSums) {
  int t = threadIdx.x;
  int base = blockIdx.x * 1024 + t * 4;
  int d0 = (base + 0 < NN) ? deg[base + 0] : 0;
  int d1 = (base + 1 < NN) ? deg[base + 1] : 0;
  int d2 = (base + 2 < NN) ? deg[base + 2] : 0;
  int d3 = (base + 3 < NN) ? deg[base + 3] : 0;
  int s = d0 + d1 + d2 + d3;
  int lane = t & 63;
  int incl = s;
  #pragma unroll
  for (int o = 1; o < 64; o <<= 1) {
    int v = __shfl_up(incl, o, 64);
    if (lane >= o) incl += v;
  }
  __shared__ int wsum[4], woff[4];
  if (lane == 63) wsum[t >> 6] = incl;
  __syncthreads();
  if (t == 0) {
    int r = 0;
    for (int w = 0; w < 4; ++w) { woff[w] = r; r += wsum[w]; }
    blockSums[blockIdx.x] = r;
  }
  __syncthreads();
  int run = woff[t >> 6] + incl - s;
  int dd[4] = {d0, d1, d2, d3};
  #pragma unroll
  for (int q = 0; q < 4; ++q) {
    int idx = base + q;
    if (idx <= NN) rowptr[idx] = run;
    run += dd[q];
  }
}

__global__ void scanB_kernel(const int* __restrict__ blockSums, int* __restrict__ blockOff, int nblk) {
  __shared__ int v[128];
  int t = threadIdx.x;
  int mine = (t < nblk) ? blockSums[t] : 0;
  v[t] = mine;
  __syncthreads();
  for (int o = 1; o < 128; o <<= 1) {
    int add = (t >= o) ? v[t - o] : 0;
    __syncthreads();
    v[t] += add;
    __syncthreads();
  }
  if (t < nblk) blockOff[t] = v[t] - mine;
}

__global__ void scanC_kernel(int* __restrict__ rowptr, int* __restrict__ cursor,
                             const int* __restrict__ blockOff) {
  int t = threadIdx.x;
  int base = blockIdx.x * 1024 + t * 4;
  int add = blockOff[blockIdx.x];
  #pragma unroll
  for (int q = 0; q < 4; ++q) {
    int idx = base + q;
    if (idx <= NN) {
      int v = rowptr[idx] + add;
      rowptr[idx] = v;
      if (idx < NN) cursor[idx] = v;
    }
  }
}

// pack src (17 bits) | etype (3 bits << 17) into one int
__global__ void fill_kernel(const int* __restrict__ src, const int* __restrict__ dst,
                            const int* __restrict__ etype,
                            int* __restrict__ cursor, int* __restrict__ csr) {
  int e = blockIdx.x * 256 + threadIdx.x;
  if (e >= NE) return;
  int d = dst[e];
  int pos = atomicAdd(&cursor[d], 1);
  csr[pos] = src[e] | (etype[e] << 17);
}

// ---------------- fused 2-layer MLP, MFMA bf16, LDS-staged ----------------
// Block = 64 rows, 4 waves. All global accesses coalesced; fragments via LDS.
// L1: wave wv owns col-tiles wv*4..wv*4+3 x row-tiles 0..3 (acc 16 tiles).
// L2: wave wv owns row-tile wv x col-tiles 0..3.
// LDS regions overlap (barrier-separated): A(64x136us) / Hs(64x264us) / Os(64x72us).

__launch_bounds__(256)
__global__ void mlp_kernel(const float* __restrict__ x,
                           const ushort_t* __restrict__ W1s, const float* __restrict__ b1,
                           const ushort_t* __restrict__ W2s, const float* __restrict__ b2,
                           ushort_t* __restrict__ mh) {
  __shared__ ushort_t S[64 * 264];  // 33792 B union
  int t = threadIdx.x;
  int wv = t >> 6, lane = t & 63;
  int quad = lane >> 4, l15 = lane & 15;
  int nb = blockIdx.x * 64;

  // stage x tile -> bf16 LDS (A), stride 136 us
  #pragma unroll
  for (int it = 0; it < 8; ++it) {
    int f = it * 256 + t;          // float4 id
    int row = f >> 5, off4 = f & 31;
    int grow = min(nb + row, NN - 1);
    float4 v = *(const float4*)&x[(size_t)grow * 128 + off4 * 4];
    union { uint2 d; ushort_t u[4]; } pk;
    pk.u[0] = f2bf(v.x); pk.u[1] = f2bf(v.y); pk.u[2] = f2bf(v.z); pk.u[3] = f2bf(v.w);
    *(uint2*)&S[row * 136 + off4 * 4] = pk.d;
  }
  __syncthreads();

  floatx4 acc1[4][4];  // [rt][ctl]
  #pragma unroll
  for (int rt = 0; rt < 4; ++rt)
    #pragma unroll
    for (int c = 0; c < 4; ++c) acc1[rt][c] = (floatx4)0.f;

  #pragma unroll
  for (int s = 0; s < 4; ++s) {
    short8 av[4];
    #pragma unroll
    for (int rt = 0; rt < 4; ++rt)
      av[rt] = *(const short8*)&S[(rt * 16 + l15) * 136 + s * 32 + quad * 8];
    #pragma unroll
    for (int c = 0; c < 4; ++c) {
      short8 bv = *(const short8*)&W1s[((s * 16 + wv * 4 + c) * 64 + lane) * 8];
      #pragma unroll
      for (int rt = 0; rt < 4; ++rt)
        acc1[rt][c] = __builtin_amdgcn_mfma_f32_16x16x32_bf16(av[rt], bv, acc1[rt][c], 0, 0, 0);
    }
  }
  __syncthreads();  // done reading A

  // hidden -> LDS (Hs), stride 264 us
  #pragma unroll
  for (int c = 0; c < 4; ++c) {
    int col = (wv * 4 + c) * 16 + l15;
    float bb = b1[col];
    #pragma unroll
    for (int rt = 0; rt < 4; ++rt)
      #pragma unroll
      for (int reg = 0; reg < 4; ++reg)
        S[(rt * 16 + quad * 4 + reg) * 264 + col] = f2bf(fmaxf(acc1[rt][c][reg] + bb, 0.f));
  }
  __syncthreads();

  floatx4 acc2[4];
  #pragma unroll
  for (int c = 0; c < 4; ++c) acc2[c] = (floatx4)0.f;
  #pragma unroll
  for (int s = 0; s < 8; ++s) {
    short8 av = *(const short8*)&S[(wv * 16 + l15) * 264 + s * 32 + quad * 8];
    #pragma unroll
    for (int c = 0; c < 4; ++c) {
      short8 bv = *(const short8*)&W2s[((s * 4 + c) * 64 + lane) * 8];
      acc2[c] = __builtin_amdgcn_mfma_f32_16x16x32_bf16(av, bv, acc2[c], 0, 0, 0);
    }
  }
  __syncthreads();  // done reading Hs

  // out -> LDS (Os), stride 72 us
  #pragma unroll
  for (int c = 0; c < 4; ++c) {
    int col = c * 16 + l15;
    float bb = b2[col];
    #pragma unroll
    for (int reg = 0; reg < 4; ++reg)
      S[(wv * 16 + quad * 4 + reg) * 72 + col] = f2bf(acc2[c][reg] + bb);
  }
  __syncthreads();

  // coalesced store: 64 rows x 64 us (8 chunks of 16B)
  #pragma unroll
  for (int it = 0; it < 2; ++it) {
    int idx = it * 256 + t;
    int row = idx >> 3, ch = idx & 7;
    int node = nb + row;
    if (node < NN) {
      short8 v = *(const short8*)&S[row * 72 + ch * 8];
      *(short8*)&mh[(size_t)node * 128 + 64 + ch * 8] = v;
    }
  }
}

// ---------------- scatter-mean aggregation: wave/node, 8-way ILP ----------------

__launch_bounds__(256)
__global__ void agg_kernel(ushort_t* __restrict__ mh, const int* __restrict__ rowptr,
                           const int* __restrict__ csr, const float* __restrict__ wtab) {
  __shared__ float wt[8];
  if (threadIdx.x < 8) wt[threadIdx.x] = wtab[threadIdx.x];
  __syncthreads();
  int node = (blockIdx.x * 256 + threadIdx.x) >> 6;
  int lane = threadIdx.x & 63;
  int s = rowptr[node], e = rowptr[node + 1];
  float acc0 = 0.f, acc1 = 0.f, acc2 = 0.f, acc3 = 0.f;
  float acc4 = 0.f, acc5 = 0.f, acc6 = 0.f, acc7 = 0.f;
  int p = s;
  for (; p + 8 <= e; p += 8) {
    int k0 = csr[p], k1 = csr[p + 1], k2 = csr[p + 2], k3 = csr[p + 3];
    int k4 = csr[p + 4], k5 = csr[p + 5], k6 = csr[p + 6], k7 = csr[p + 7];
    float v0 = bf2f(mh[(size_t)(k0 & 0x1FFFF) * 128 + 64 + lane]);
    float v1 = bf2f(mh[(size_t)(k1 & 0x1FFFF) * 128 + 64 + lane]);
    float v2 = bf2f(mh[(size_t)(k2 & 0x1FFFF) * 128 + 64 + lane]);
    float v3 = bf2f(mh[(size_t)(k3 & 0x1FFFF) * 128 + 64 + lane]);
    float v4 = bf2f(mh[(size_t)(k4 & 0x1FFFF) * 128 + 64 + lane]);
    float v5 = bf2f(mh[(size_t)(k5 & 0x1FFFF) * 128 + 64 + lane]);
    float v6 = bf2f(mh[(size_t)(k6 & 0x1FFFF) * 128 + 64 + lane]);
    float v7 = bf2f(mh[(size_t)(k7 & 0x1FFFF) * 128 + 64 + lane]);
    acc0 += wt[k0 >> 17] * v0;
    acc1 += wt[k1 >> 17] * v1;
    acc2 += wt[k2 >> 17] * v2;
    acc3 += wt[k3 >> 17] * v3;
    acc4 += wt[k4 >> 17] * v4;
    acc5 += wt[k5 >> 17] * v5;
    acc6 += wt[k6 >> 17] * v6;
    acc7 += wt[k7 >> 17] * v7;
  }
  for (; p + 4 <= e; p += 4) {
    int k0 = csr[p], k1 = csr[p + 1], k2 = csr[p + 2], k3 = csr[p + 3];
    float v0 = bf2f(mh[(size_t)(k0 & 0x1FFFF) * 128 + 64 + lane]);
    float v1 = bf2f(mh[(size_t)(k1 & 0x1FFFF) * 128 + 64 + lane]);
    float v2 = bf2f(mh[(size_t)(k2 & 0x1FFFF) * 128 + 64 + lane]);
    float v3 = bf2f(mh[(size_t)(k3 & 0x1FFFF) * 128 + 64 + lane]);
    acc0 += wt[k0 >> 17] * v0;
    acc1 += wt[k1 >> 17] * v1;
    acc2 += wt[k2 >> 17] * v2;
    acc3 += wt[k3 >> 17] * v3;
  }
  for (; p < e; ++p) {
    int k = csr[p];
    acc0 += wt[k >> 17] * bf2f(mh[(size_t)(k & 0x1FFFF) * 128 + 64 + lane]);
  }
  float acc = ((acc0 + acc1) + (acc2 + acc3)) + ((acc4 + acc5) + (acc6 + acc7));
  mh[(size_t)node * 128 + lane] = f2bf(acc / fmaxf((float)(e - s), 1.f));
}

// ---------------- GRU: MFMA GEMM, LDS-staged A + coalesced out ----------------
// Block = 64 rows, 4 waves. Wave wv owns within-gate col-tile wv for all 4
// gates x 4 row-tiles -> gates colocated in-lane. A staged in LDS (stride 136).

__launch_bounds__(256)
__global__ void gru_kernel(const ushort_t* __restrict__ mhin, const ushort_t* __restrict__ Wcs,
                           const float* __restrict__ b_ih, const float* __restrict__ b_hh,
                           ushort_t* __restrict__ mhout) {
  __shared__ ushort_t As[64 * 136];  // 17408 B
  __shared__ ushort_t Os[64 * 72];   //  9216 B
  int t = threadIdx.x;
  int wv = t >> 6, lane = t & 63;
  int quad = lane >> 4, l15 = lane & 15;
  int nb = blockIdx.x * 64;

  // stage mh tile (64 x 128 us) coalesced
  #pragma unroll
  for (int it = 0; it < 4; ++it) {
    int idx = it * 256 + t;
    int row = idx >> 4, ch = idx & 15;
    int grow = min(nb + row, NN - 1);
    short8 v = *(const short8*)&mhin[(size_t)grow * 128 + ch * 8];
    *(short8*)&As[row * 136 + ch * 8] = v;
  }
  __syncthreads();

  floatx4 acc[4][4];  // [rt][gate]
  #pragma unroll
  for (int rt = 0; rt < 4; ++rt)
    #pragma unroll
    for (int g = 0; g < 4; ++g) acc[rt][g] = (floatx4)0.f;

  #pragma unroll
  for (int s = 0; s < 4; ++s) {
    short8 av[4];
    #pragma unroll
    for (int rt = 0; rt < 4; ++rt)
      av[rt] = *(const short8*)&As[(rt * 16 + l15) * 136 + s * 32 + quad * 8];
    #pragma unroll
    for (int g = 0; g < 4; ++g) {
      short8 bv = *(const short8*)&Wcs[((s * 16 + g * 4 + wv) * 64 + lane) * 8];
      #pragma unroll
      for (int rt = 0; rt < 4; ++rt)
        acc[rt][g] = __builtin_amdgcn_mfma_f32_16x16x32_bf16(av[rt], bv, acc[rt][g], 0, 0, 0);
    }
  }

  int j = wv * 16 + l15;
  float bir = b_ih[j] + b_hh[j];
  float biz = b_ih[64 + j] + b_hh[64 + j];
  float bin_ = b_ih[128 + j];
  float bhn = b_hh[128 + j];
  #pragma unroll
  for (int rt = 0; rt < 4; ++rt) {
    #pragma unroll
    for (int reg = 0; reg < 4; ++reg) {
      int lrow = rt * 16 + quad * 4 + reg;
      float r = sigmoidf_(acc[rt][0][reg] + bir);
      float z = sigmoidf_(acc[rt][1][reg] + biz);
      float n = tanhf_fast(acc[rt][2][reg] + bin_ + r * (acc[rt][3][reg] + bhn));
      float hp = bf2f(As[lrow * 136 + 64 + j]);
      Os[lrow * 72 + j] = f2bf((1.f - z) * n + z * hp);
    }
  }
  __syncthreads();

  #pragma unroll
  for (int it = 0; it < 2; ++it) {
    int idx = it * 256 + t;
    int row = idx >> 3, ch = idx & 7;
    int node = nb + row;
    if (node < NN) {
      short8 v = *(const short8*)&Os[row * 72 + ch * 8];
      *(short8*)&mhout[(size_t)node * 128 + 64 + ch * 8] = v;
    }
  }
}

// ---------------- pooling + head ----------------

__global__ void scatter_kernel(const int* __restrict__ diff, int* __restrict__ flag) {
  int i = blockIdx.x * 256 + threadIdx.x;
  if (i < NDIFF) flag[diff[i]] = 1;
}

__global__ void pool_kernel(const ushort_t* __restrict__ mh, const int* __restrict__ flag,
                            float* __restrict__ pooled) {
  int gw = (blockIdx.x * 256 + threadIdx.x) >> 6;
  int lane = threadIdx.x & 63;
  const int chunk = (NN + 1023) / 1024;  // 98
  int n0 = gw * chunk;
  int n1 = min(n0 + chunk, NN);
  float base = 0.f, fl = 0.f, cnt = 0.f;
  int n = n0;
  for (; n + 4 <= n1; n += 4) {
    float v0 = bf2f(mh[(size_t)(n + 0) * 128 + 64 + lane]);
    float v1 = bf2f(mh[(size_t)(n + 1) * 128 + 64 + lane]);
    float v2 = bf2f(mh[(size_t)(n + 2) * 128 + 64 + lane]);
    float v3 = bf2f(mh[(size_t)(n + 3) * 128 + 64 + lane]);
    int f0 = flag[n + 0], f1 = flag[n + 1], f2 = flag[n + 2], f3 = flag[n + 3];
    base += (v0 + v1) + (v2 + v3);
    if (f0) { fl += v0; cnt += 1.f; }
    if (f1) { fl += v1; cnt += 1.f; }
    if (f2) { fl += v2; cnt += 1.f; }
    if (f3) { fl += v3; cnt += 1.f; }
  }
  for (; n < n1; ++n) {
    float v = bf2f(mh[(size_t)n * 128 + 64 + lane]);
    base += v;
    if (flag[n]) { fl += v; cnt += 1.f; }
  }
  atomicAdd(&pooled[lane], base);
  atomicAdd(&pooled[64 + lane], fl);
  if (lane == 0) atomicAdd(&pooled[128], cnt);
}

__global__ void final_kernel(const float* __restrict__ pooled,
                             const float* __restrict__ fc1_w, const float* __restrict__ fc1_b,
                             const float* __restrict__ fc2_w, const float* __restrict__ fc2_b,
                             const float* __restrict__ w_imp, float* __restrict__ out) {
  __shared__ float p[64];
  __shared__ float hid[256];
  __shared__ float o[2];
  int t = threadIdx.x;
  float wpos = softplusf_(w_imp[0]);
  if (t < 64) {
    float num = pooled[t] + wpos * pooled[64 + t];
    float den = (float)NN + wpos * pooled[128];
    p[t] = num / den;
  }
  __syncthreads();
  {
    float a = 0.f;
    for (int k = 0; k < 64; ++k) a += p[k] * fc1_w[t * 64 + k];
    hid[t] = fmaxf(a + fc1_b[t], 0.f);
  }
  __syncthreads();
  if (t < 2) {
    float a = 0.f;
    for (int k = 0; k < 256; ++k) a += hid[k] * fc2_w[t * 256 + k];
    o[t] = a + fc2_b[t];
  }
  __syncthreads();
  if (t == 0) {
    float mx = fmaxf(o[0], o[1]);
    float lse = mx + logf(__expf(o[0] - mx) + __expf(o[1] - mx));
    out[0] = o[0] - lse;
    out[1] = o[1] - lse;
  }
}

// ---------------- launch ----------------

extern "C" void kernel_launch(void* const* d_in, const int* in_sizes, int n_in,
                              void* d_out, int out_size, void* d_ws, size_t ws_size,
                              hipStream_t stream) {
  const float* x        = (const float*)d_in[0];
  const int*   ei       = (const int*)d_in[1];
  const int*   etype    = (const int*)d_in[2];
  const int*   diff_idx = (const int*)d_in[3];
  const float* lin1_w   = (const float*)d_in[4];
  const float* lin1_b   = (const float*)d_in[5];
  const float* lin2_w   = (const float*)d_in[6];
  const float* lin2_b   = (const float*)d_in[7];
  const float* gru_w_ih = (const float*)d_in[8];
  const float* gru_w_hh = (const float*)d_in[9];
  const float* gru_b_ih = (const float*)d_in[10];
  const float* gru_b_hh = (const float*)d_in[11];
  const float* etw      = (const float*)d_in[12];
  const float* fc1_w    = (const float*)d_in[13];
  const float* fc1_b    = (const float*)d_in[14];
  const float* fc2_w    = (const float*)d_in[15];
  const float* fc2_b    = (const float*)d_in[16];
  const float* w_imp    = (const float*)d_in[17];
  float* out = (float*)d_out;

  char* ws = (char*)d_ws;
  size_t off = 0;
  auto alloc = [&](size_t bytes) -> void* {
    void* p = ws + off;
    off += (bytes + 255) & ~(size_t)255;
    return p;
  };
  ushort_t* mh0   = (ushort_t*)alloc((size_t)NN * 128 * 2);
  ushort_t* mh1   = (ushort_t*)alloc((size_t)NN * 128 * 2);
  int*   csr      = (int*)  alloc((size_t)NE * 4);
  ushort_t* W1s   = (ushort_t*)alloc(128 * 256 * 2);
  ushort_t* W2s   = (ushort_t*)alloc(256 * 64 * 2);
  ushort_t* Wcs   = (ushort_t*)alloc(128 * 256 * 2);
  float* wtab     = (float*)alloc(8 * 4);
  int*   rowptr   = (int*)  alloc((size_t)(NN + 1) * 4);
  int*   cursor   = (int*)  alloc((size_t)NN * 4);
  int*   blockSums = (int*)alloc(128 * 4);
  int*   blockOff  = (int*)alloc(128 * 4);
  int*   zbase    = (int*)  alloc((size_t)(2 * NN + 129) * 4);
  int* deg    = zbase;
  int* flag   = zbase + NN;
  float* pooled = (float*)(zbase + 2 * NN);

  const int nscan = (NN + 1023) / 1024;  // 98
  const int ngemm = (NN + 63) / 64;      // 1563

  zero_kernel<<<(2 * NN + 129 + 255) / 256, 256, 0, stream>>>(zbase, 2 * NN + 129);
  prep_w_kernel<<<320, 256, 0, stream>>>(lin1_w, lin2_w, gru_w_ih, gru_w_hh, etw,
                                         W1s, W2s, Wcs, wtab);
  count_kernel<<<(NE + 255) / 256, 256, 0, stream>>>(ei + NE, deg);
  scanA_kernel<<<nscan, 256, 0, stream>>>(deg, rowptr, blockSums);
  scanB_kernel<<<1, 128, 0, stream>>>(blockSums, blockOff, nscan);
  scanC_kernel<<<nscan, 256, 0, stream>>>(rowptr, cursor, blockOff);
  fill_kernel<<<(NE + 255) / 256, 256, 0, stream>>>(ei, ei + NE, etype, cursor, csr);
  mlp_kernel<<<ngemm, 256, 0, stream>>>(x, W1s, lin1_b, W2s, lin2_b, mh0);

  ushort_t* ha = mh0;
  ushort_t* hb = mh1;
  for (int it = 0; it < 3; ++it) {
    agg_kernel<<<NN / 4, 256, 0, stream>>>(ha, rowptr, csr, wtab);
    gru_kernel<<<ngemm, 256, 0, stream>>>(ha, Wcs, gru_b_ih, gru_b_hh, hb);
    ushort_t* tmp = ha; ha = hb; hb = tmp;
  }
  scatter_kernel<<<(NDIFF + 255) / 256, 256, 0, stream>>>(diff_idx, flag);
  pool_kernel<<<256, 256, 0, stream>>>(ha, flag, pooled);
  final_kernel<<<1, 256, 0, stream>>>(pooled, fc1_w, fc1_b, fc2_w, fc2_b, w_imp, out);
}

// Round 6
// 465.319 us; speedup vs baseline: 5.6986x; 1.1500x over previous
//
#include <hip/hip_runtime.h>
#include <math.h>

#define NN 100000
#define NE 1200000
#define NDIFF 1000
#define NPART 8
#define PSIZE 12500   // NN / NPART exactly

typedef short short8 __attribute__((ext_vector_type(8)));
typedef float floatx4 __attribute__((ext_vector_type(4)));
typedef unsigned short ushort_t;

__device__ __forceinline__ float softplusf_(float x) {
  return fmaxf(x, 0.f) + logf(1.f + __expf(-fabsf(x)));
}
__device__ __forceinline__ float sigmoidf_(float x) {
  return 1.f / (1.f + __expf(-x));
}
__device__ __forceinline__ float tanhf_fast(float x) {
  float ax = fabsf(x);
  float e = __expf(-2.f * ax);
  float t = (1.f - e) / (1.f + e);
  return x < 0.f ? -t : t;
}
__device__ __forceinline__ ushort_t f2bf(float f) {
  unsigned u = __float_as_uint(f);
  unsigned r = (u + 0x7FFFu + ((u >> 16) & 1u)) >> 16;
  return (ushort_t)r;
}
__device__ __forceinline__ float bf2f(ushort_t s) {
  return __uint_as_float(((unsigned)s) << 16);
}

// ---------------- setup kernels ----------------

__global__ void zero_kernel(int* __restrict__ p, int n) {
  int i = blockIdx.x * 256 + threadIdx.x;
  if (i < n) p[i] = 0;
}

// rank[e] = arrival index of edge e within its dst bucket; deg accumulates.
__global__ void rank_kernel(const int* __restrict__ dst, int* __restrict__ deg,
                            int* __restrict__ rank) {
  int e = blockIdx.x * 256 + threadIdx.x;
  if (e < NE) rank[e] = atomicAdd(&deg[dst[e]], 1);
}

// Fragment-major bf16 weights: B-fragment of (s,ct) = 64 lanes x 8 bf16 (1KB).
// lane = quad*16+l15; element j: W[col=ct*16+l15][k=s*32+quad*8+j].
__global__ void prep_w_kernel(const float* __restrict__ lin1_w, const float* __restrict__ lin2_w,
                              const float* __restrict__ w_ih, const float* __restrict__ w_hh,
                              const float* __restrict__ etw,
                              ushort_t* __restrict__ W1s, ushort_t* __restrict__ W2s,
                              ushort_t* __restrict__ Wcs, float* __restrict__ wtab) {
  int i = blockIdx.x * 256 + threadIdx.x;  // 0..81919
  if (i < 8) wtab[i] = softplusf_(etw[i]);
  if (i < 32768) {
    int fi = i >> 9, lane = (i >> 3) & 63, j = i & 7;
    int s = fi >> 4, ct = fi & 15;
    int quad = lane >> 4, l15 = lane & 15;
    int col = ct * 16 + l15, k = s * 32 + quad * 8 + j;
    W1s[i] = f2bf(lin1_w[col * 128 + k]);
  } else if (i < 49152) {
    int i2 = i - 32768;
    int fi = i2 >> 9, lane = (i2 >> 3) & 63, j = i2 & 7;
    int s = fi >> 2, ct = fi & 3;
    int quad = lane >> 4, l15 = lane & 15;
    int col = ct * 16 + l15, k = s * 32 + quad * 8 + j;
    W2s[i2] = f2bf(lin2_w[col * 256 + k]);
  } else {
    int i3 = i - 49152;
    int fi = i3 >> 9, lane = (i3 >> 3) & 63, j = i3 & 7;
    int s = fi >> 4, ct = fi & 15;
    int quad = lane >> 4, l15 = lane & 15;
    int jj = ct * 16 + l15, k = s * 32 + quad * 8 + j;
    float v;
    if (jj < 128)      v = (k < 64) ? w_ih[jj * 64 + k] : w_hh[jj * 64 + (k - 64)];
    else if (jj < 192) v = (k < 64) ? w_ih[jj * 64 + k] : 0.f;
    else               v = (k < 64) ? 0.f : w_hh[(jj - 64) * 64 + (k - 64)];
    Wcs[i3] = f2bf(v);
  }
}

// ---------------- exclusive scan (3 kernels) ----------------

__global__ void scanA_kernel(const int* __restrict__ deg, int* __restrict__ rowptr,
                             int* __restrict__ blockSums) {
  int t = threadIdx.x;
  int base = blockIdx.x * 1024 + t * 4;
  int d0 = (base + 0 < NN) ? deg[base + 0] : 0;
  int d1 = (base + 1 < NN) ? deg[base + 1] : 0;
  int d2 = (base + 2 < NN) ? deg[base + 2] : 0;
  int d3 = (base + 3 < NN) ? deg[base + 3] : 0;
  int s = d0 + d1 + d2 + d3;
  int lane = t & 63;
  int incl = s;
  #pragma unroll
  for (int o = 1; o < 64; o <<= 1) {
    int v = __shfl_up(incl, o, 64);
    if (lane >= o) incl += v;
  }
  __shared__ int wsum[4], woff[4];
  if (lane == 63) wsum[t >> 6] = incl;
  __syncthreads();
  if (t == 0) {
    int r = 0;
    for (int w = 0; w < 4; ++w) { woff[w] = r; r += wsum[w]; }
    blockSums[blockIdx.x] = r;
  }
  __syncthreads();
  int run = woff[t >> 6] + incl - s;
  int dd[4] = {d0, d1, d2, d3};
  #pragma unroll
  for (int q = 0; q < 4; ++q) {
    int idx = base + q;
    if (idx <= NN) rowptr[idx] = run;
    run += dd[q];
  }
}

__global__ void scanB_kernel(const int* __restrict__ blockSums, int* __restrict__ blockOff, int nblk) {
  __shared__ int v[128];
  int t = threadIdx.x;
  int mine = (t < nblk) ? blockSums[t] : 0;
  v[t] = mine;
  __syncthreads();
  for (int o = 1; o < 128; o <<= 1) {
    int add = (t >= o) ? v[t - o] : 0;
    __syncthreads();
    v[t] += add;
    __syncthreads();
  }
  if (t < nblk) blockOff[t] = v[t] - mine;
}

__global__ void scanC_kernel(int* __restrict__ rowptr, const int* __restrict__ blockOff) {
  int t = threadIdx.x;
  int base = blockIdx.x * 1024 + t * 4;
  int add = blockOff[blockIdx.x];
  #pragma unroll
  for (int q = 0; q < 4; ++q) {
    int idx = base + q;
    if (idx <= NN) rowptr[idx] += add;
  }
}

// ---------------- partitioned atomic-free CSR fill ----------------
// Block (b&7)=p handles node partition p (XCD round-robin affinity) over edge
// slice (b>>3). csr writes for partition p all come from one XCD -> write
// combining in its L2. pack src | etype<<17.
#define SLICE 2048
__global__ void fill_part_kernel(const int* __restrict__ src, const int* __restrict__ dst,
                                 const int* __restrict__ etype, const int* __restrict__ rank,
                                 const int* __restrict__ rowptr, int* __restrict__ csr) {
  int p = blockIdx.x & 7;
  int base = (blockIdx.x >> 3) * SLICE;
  const int lo = p * PSIZE, hi = lo + PSIZE;
  #pragma unroll
  for (int it = 0; it < SLICE / 256; ++it) {
    int e = base + it * 256 + threadIdx.x;
    if (e < NE) {
      int d = dst[e];
      if (d >= lo && d < hi) {
        int pos = rowptr[d] + rank[e];
        csr[pos] = src[e] | (etype[e] << 17);
      }
    }
  }
}

// ---------------- fused 2-layer MLP, MFMA bf16, LDS-staged ----------------

__launch_bounds__(256)
__global__ void mlp_kernel(const float* __restrict__ x,
                           const ushort_t* __restrict__ W1s, const float* __restrict__ b1,
                           const ushort_t* __restrict__ W2s, const float* __restrict__ b2,
                           ushort_t* __restrict__ mh) {
  __shared__ ushort_t S[64 * 264];  // 33792 B union
  int t = threadIdx.x;
  int wv = t >> 6, lane = t & 63;
  int quad = lane >> 4, l15 = lane & 15;
  int nb = blockIdx.x * 64;

  #pragma unroll
  for (int it = 0; it < 8; ++it) {
    int f = it * 256 + t;
    int row = f >> 5, off4 = f & 31;
    int grow = min(nb + row, NN - 1);
    float4 v = *(const float4*)&x[(size_t)grow * 128 + off4 * 4];
    union { uint2 d; ushort_t u[4]; } pk;
    pk.u[0] = f2bf(v.x); pk.u[1] = f2bf(v.y); pk.u[2] = f2bf(v.z); pk.u[3] = f2bf(v.w);
    *(uint2*)&S[row * 136 + off4 * 4] = pk.d;
  }
  __syncthreads();

  floatx4 acc1[4][4];
  #pragma unroll
  for (int rt = 0; rt < 4; ++rt)
    #pragma unroll
    for (int c = 0; c < 4; ++c) acc1[rt][c] = (floatx4)0.f;

  #pragma unroll
  for (int s = 0; s < 4; ++s) {
    short8 av[4];
    #pragma unroll
    for (int rt = 0; rt < 4; ++rt)
      av[rt] = *(const short8*)&S[(rt * 16 + l15) * 136 + s * 32 + quad * 8];
    #pragma unroll
    for (int c = 0; c < 4; ++c) {
      short8 bv = *(const short8*)&W1s[((s * 16 + wv * 4 + c) * 64 + lane) * 8];
      #pragma unroll
      for (int rt = 0; rt < 4; ++rt)
        acc1[rt][c] = __builtin_amdgcn_mfma_f32_16x16x32_bf16(av[rt], bv, acc1[rt][c], 0, 0, 0);
    }
  }
  __syncthreads();

  #pragma unroll
  for (int c = 0; c < 4; ++c) {
    int col = (wv * 4 + c) * 16 + l15;
    float bb = b1[col];
    #pragma unroll
    for (int rt = 0; rt < 4; ++rt)
      #pragma unroll
      for (int reg = 0; reg < 4; ++reg)
        S[(rt * 16 + quad * 4 + reg) * 264 + col] = f2bf(fmaxf(acc1[rt][c][reg] + bb, 0.f));
  }
  __syncthreads();

  floatx4 acc2[4];
  #pragma unroll
  for (int c = 0; c < 4; ++c) acc2[c] = (floatx4)0.f;
  #pragma unroll
  for (int s = 0; s < 8; ++s) {
    short8 av = *(const short8*)&S[(wv * 16 + l15) * 264 + s * 32 + quad * 8];
    #pragma unroll
    for (int c = 0; c < 4; ++c) {
      short8 bv = *(const short8*)&W2s[((s * 4 + c) * 64 + lane) * 8];
      acc2[c] = __builtin_amdgcn_mfma_f32_16x16x32_bf16(av, bv, acc2[c], 0, 0, 0);
    }
  }
  __syncthreads();

  #pragma unroll
  for (int c = 0; c < 4; ++c) {
    int col = c * 16 + l15;
    float bb = b2[col];
    #pragma unroll
    for (int reg = 0; reg < 4; ++reg)
      S[(wv * 16 + quad * 4 + reg) * 72 + col] = f2bf(acc2[c][reg] + bb);
  }
  __syncthreads();

  #pragma unroll
  for (int it = 0; it < 2; ++it) {
    int idx = it * 256 + t;
    int row = idx >> 3, ch = idx & 7;
    int node = nb + row;
    if (node < NN) {
      short8 v = *(const short8*)&S[row * 72 + ch * 8];
      *(short8*)&mh[(size_t)node * 128 + 64 + ch * 8] = v;
    }
  }
}

// ---------------- scatter-mean aggregation: half-wave/node, 8-way ILP ----------
// 2 nodes per wave (32 lanes x 4B = full 128B h-row), partition-swizzled so
// csr/rowptr/m-writes hit the XCD-local L2 left dirty by fill_part.

__launch_bounds__(256)
__global__ void agg_kernel(ushort_t* __restrict__ mh, const int* __restrict__ rowptr,
                           const int* __restrict__ csr, const float* __restrict__ wtab) {
  __shared__ float wt[8];
  if (threadIdx.x < 8) wt[threadIdx.x] = wtab[threadIdx.x];
  __syncthreads();
  int p8 = blockIdx.x & 7, q = blockIdx.x >> 3;
  int local = q * 8 + (threadIdx.x >> 5);
  if (local >= PSIZE) return;
  int node = p8 * PSIZE + local;
  int c = threadIdx.x & 31;
  int s = rowptr[node], e = rowptr[node + 1];
  float aL[8], aH[8];
  #pragma unroll
  for (int i = 0; i < 8; ++i) { aL[i] = 0.f; aH[i] = 0.f; }
  int p = s;
  for (; p + 8 <= e; p += 8) {
    #pragma unroll
    for (int i = 0; i < 8; ++i) {
      int k = csr[p + i];
      unsigned v = *(const unsigned*)&mh[(size_t)(k & 0x1FFFF) * 128 + 64 + c * 2];
      float w = wt[k >> 17];
      aL[i] += w * __uint_as_float(v << 16);
      aH[i] += w * __uint_as_float(v & 0xFFFF0000u);
    }
  }
  for (; p < e; ++p) {
    int k = csr[p];
    unsigned v = *(const unsigned*)&mh[(size_t)(k & 0x1FFFF) * 128 + 64 + c * 2];
    float w = wt[k >> 17];
    aL[0] += w * __uint_as_float(v << 16);
    aH[0] += w * __uint_as_float(v & 0xFFFF0000u);
  }
  float l = ((aL[0] + aL[1]) + (aL[2] + aL[3])) + ((aL[4] + aL[5]) + (aL[6] + aL[7]));
  float h = ((aH[0] + aH[1]) + (aH[2] + aH[3])) + ((aH[4] + aH[5]) + (aH[6] + aH[7]));
  float invd = 1.f / fmaxf((float)(e - s), 1.f);
  unsigned outv = (unsigned)f2bf(l * invd) | ((unsigned)f2bf(h * invd) << 16);
  *(unsigned*)&mh[(size_t)node * 128 + c * 2] = outv;
}

// ---------------- GRU: MFMA GEMM, LDS-staged A + coalesced out ----------------

__launch_bounds__(256)
__global__ void gru_kernel(const ushort_t* __restrict__ mhin, const ushort_t* __restrict__ Wcs,
                           const float* __restrict__ b_ih, const float* __restrict__ b_hh,
                           ushort_t* __restrict__ mhout) {
  __shared__ ushort_t As[64 * 136];
  __shared__ ushort_t Os[64 * 72];
  int t = threadIdx.x;
  int wv = t >> 6, lane = t & 63;
  int quad = lane >> 4, l15 = lane & 15;
  int nb = blockIdx.x * 64;

  #pragma unroll
  for (int it = 0; it < 4; ++it) {
    int idx = it * 256 + t;
    int row = idx >> 4, ch = idx & 15;
    int grow = min(nb + row, NN - 1);
    short8 v = *(const short8*)&mhin[(size_t)grow * 128 + ch * 8];
    *(short8*)&As[row * 136 + ch * 8] = v;
  }
  __syncthreads();

  floatx4 acc[4][4];
  #pragma unroll
  for (int rt = 0; rt < 4; ++rt)
    #pragma unroll
    for (int g = 0; g < 4; ++g) acc[rt][g] = (floatx4)0.f;

  #pragma unroll
  for (int s = 0; s < 4; ++s) {
    short8 av[4];
    #pragma unroll
    for (int rt = 0; rt < 4; ++rt)
      av[rt] = *(const short8*)&As[(rt * 16 + l15) * 136 + s * 32 + quad * 8];
    #pragma unroll
    for (int g = 0; g < 4; ++g) {
      short8 bv = *(const short8*)&Wcs[((s * 16 + g * 4 + wv) * 64 + lane) * 8];
      #pragma unroll
      for (int rt = 0; rt < 4; ++rt)
        acc[rt][g] = __builtin_amdgcn_mfma_f32_16x16x32_bf16(av[rt], bv, acc[rt][g], 0, 0, 0);
    }
  }

  int j = wv * 16 + l15;
  float bir = b_ih[j] + b_hh[j];
  float biz = b_ih[64 + j] + b_hh[64 + j];
  float bin_ = b_ih[128 + j];
  float bhn = b_hh[128 + j];
  #pragma unroll
  for (int rt = 0; rt < 4; ++rt) {
    #pragma unroll
    for (int reg = 0; reg < 4; ++reg) {
      int lrow = rt * 16 + quad * 4 + reg;
      float r = sigmoidf_(acc[rt][0][reg] + bir);
      float z = sigmoidf_(acc[rt][1][reg] + biz);
      float n = tanhf_fast(acc[rt][2][reg] + bin_ + r * (acc[rt][3][reg] + bhn));
      float hp = bf2f(As[lrow * 136 + 64 + j]);
      Os[lrow * 72 + j] = f2bf((1.f - z) * n + z * hp);
    }
  }
  __syncthreads();

  #pragma unroll
  for (int it = 0; it < 2; ++it) {
    int idx = it * 256 + t;
    int row = idx >> 3, ch = idx & 7;
    int node = nb + row;
    if (node < NN) {
      short8 v = *(const short8*)&Os[row * 72 + ch * 8];
      *(short8*)&mhout[(size_t)node * 128 + 64 + ch * 8] = v;
    }
  }
}

// ---------------- pooling + head ----------------

__global__ void scatter_kernel(const int* __restrict__ diff, int* __restrict__ flag) {
  int i = blockIdx.x * 256 + threadIdx.x;
  if (i < NDIFF) flag[diff[i]] = 1;
}

__global__ void pool_kernel(const ushort_t* __restrict__ mh, const int* __restrict__ flag,
                            float* __restrict__ pooled) {
  int gw = (blockIdx.x * 256 + threadIdx.x) >> 6;
  int lane = threadIdx.x & 63;
  const int chunk = (NN + 1023) / 1024;  // 98
  int n0 = gw * chunk;
  int n1 = min(n0 + chunk, NN);
  float base = 0.f, fl = 0.f, cnt = 0.f;
  int n = n0;
  for (; n + 4 <= n1; n += 4) {
    float v0 = bf2f(mh[(size_t)(n + 0) * 128 + 64 + lane]);
    float v1 = bf2f(mh[(size_t)(n + 1) * 128 + 64 + lane]);
    float v2 = bf2f(mh[(size_t)(n + 2) * 128 + 64 + lane]);
    float v3 = bf2f(mh[(size_t)(n + 3) * 128 + 64 + lane]);
    int f0 = flag[n + 0], f1 = flag[n + 1], f2 = flag[n + 2], f3 = flag[n + 3];
    base += (v0 + v1) + (v2 + v3);
    if (f0) { fl += v0; cnt += 1.f; }
    if (f1) { fl += v1; cnt += 1.f; }
    if (f2) { fl += v2; cnt += 1.f; }
    if (f3) { fl += v3; cnt += 1.f; }
  }
  for (; n < n1; ++n) {
    float v = bf2f(mh[(size_t)n * 128 + 64 + lane]);
    base += v;
    if (flag[n]) { fl += v; cnt += 1.f; }
  }
  atomicAdd(&pooled[lane], base);
  atomicAdd(&pooled[64 + lane], fl);
  if (lane == 0) atomicAdd(&pooled[128], cnt);
}

__global__ void final_kernel(const float* __restrict__ pooled,
                             const float* __restrict__ fc1_w, const float* __restrict__ fc1_b,
                             const float* __restrict__ fc2_w, const float* __restrict__ fc2_b,
                             const float* __restrict__ w_imp, float* __restrict__ out) {
  __shared__ float p[64];
  __shared__ float hid[256];
  __shared__ float o[2];
  int t = threadIdx.x;
  float wpos = softplusf_(w_imp[0]);
  if (t < 64) {
    float num = pooled[t] + wpos * pooled[64 + t];
    float den = (float)NN + wpos * pooled[128];
    p[t] = num / den;
  }
  __syncthreads();
  {
    float a = 0.f;
    for (int k = 0; k < 64; ++k) a += p[k] * fc1_w[t * 64 + k];
    hid[t] = fmaxf(a + fc1_b[t], 0.f);
  }
  __syncthreads();
  if (t < 2) {
    float a = 0.f;
    for (int k = 0; k < 256; ++k) a += hid[k] * fc2_w[t * 256 + k];
    o[t] = a + fc2_b[t];
  }
  __syncthreads();
  if (t == 0) {
    float mx = fmaxf(o[0], o[1]);
    float lse = mx + logf(__expf(o[0] - mx) + __expf(o[1] - mx));
    out[0] = o[0] - lse;
    out[1] = o[1] - lse;
  }
}

// ---------------- launch ----------------

extern "C" void kernel_launch(void* const* d_in, const int* in_sizes, int n_in,
                              void* d_out, int out_size, void* d_ws, size_t ws_size,
                              hipStream_t stream) {
  const float* x        = (const float*)d_in[0];
  const int*   ei       = (const int*)d_in[1];
  const int*   etype    = (const int*)d_in[2];
  const int*   diff_idx = (const int*)d_in[3];
  const float* lin1_w   = (const float*)d_in[4];
  const float* lin1_b   = (const float*)d_in[5];
  const float* lin2_w   = (const float*)d_in[6];
  const float* lin2_b   = (const float*)d_in[7];
  const float* gru_w_ih = (const float*)d_in[8];
  const float* gru_w_hh = (const float*)d_in[9];
  const float* gru_b_ih = (const float*)d_in[10];
  const float* gru_b_hh = (const float*)d_in[11];
  const float* etw      = (const float*)d_in[12];
  const float* fc1_w    = (const float*)d_in[13];
  const float* fc1_b    = (const float*)d_in[14];
  const float* fc2_w    = (const float*)d_in[15];
  const float* fc2_b    = (const float*)d_in[16];
  const float* w_imp    = (const float*)d_in[17];
  float* out = (float*)d_out;

  char* ws = (char*)d_ws;
  size_t off = 0;
  auto alloc = [&](size_t bytes) -> void* {
    void* p = ws + off;
    off += (bytes + 255) & ~(size_t)255;
    return p;
  };
  ushort_t* mh0   = (ushort_t*)alloc((size_t)NN * 128 * 2);
  ushort_t* mh1   = (ushort_t*)alloc((size_t)NN * 128 * 2);
  int*   csr      = (int*)  alloc((size_t)NE * 4);
  int*   rank     = (int*)  alloc((size_t)NE * 4);
  ushort_t* W1s   = (ushort_t*)alloc(128 * 256 * 2);
  ushort_t* W2s   = (ushort_t*)alloc(256 * 64 * 2);
  ushort_t* Wcs   = (ushort_t*)alloc(128 * 256 * 2);
  float* wtab     = (float*)alloc(8 * 4);
  int*   rowptr   = (int*)  alloc((size_t)(NN + 1) * 4);
  int*   blockSums = (int*)alloc(128 * 4);
  int*   blockOff  = (int*)alloc(128 * 4);
  int*   zbase    = (int*)  alloc((size_t)(2 * NN + 129) * 4);
  int* deg    = zbase;
  int* flag   = zbase + NN;
  float* pooled = (float*)(zbase + 2 * NN);

  const int nscan = (NN + 1023) / 1024;            // 98
  const int ngemm = (NN + 63) / 64;                // 1563
  const int nfill = ((NE + SLICE - 1) / SLICE) * 8;  // 586*8 = 4688
  const int nagg  = ((PSIZE + 7) / 8) * 8;         // 1563*8 = 12504

  zero_kernel<<<(2 * NN + 129 + 255) / 256, 256, 0, stream>>>(zbase, 2 * NN + 129);
  prep_w_kernel<<<320, 256, 0, stream>>>(lin1_w, lin2_w, gru_w_ih, gru_w_hh, etw,
                                         W1s, W2s, Wcs, wtab);
  rank_kernel<<<(NE + 255) / 256, 256, 0, stream>>>(ei + NE, deg, rank);
  scanA_kernel<<<nscan, 256, 0, stream>>>(deg, rowptr, blockSums);
  scanB_kernel<<<1, 128, 0, stream>>>(blockSums, blockOff, nscan);
  scanC_kernel<<<nscan, 256, 0, stream>>>(rowptr, blockOff);
  fill_part_kernel<<<nfill, 256, 0, stream>>>(ei, ei + NE, etype, rank, rowptr, csr);
  mlp_kernel<<<ngemm, 256, 0, stream>>>(x, W1s, lin1_b, W2s, lin2_b, mh0);

  ushort_t* ha = mh0;
  ushort_t* hb = mh1;
  for (int it = 0; it < 3; ++it) {
    agg_kernel<<<nagg, 256, 0, stream>>>(ha, rowptr, csr, wtab);
    gru_kernel<<<ngemm, 256, 0, stream>>>(ha, Wcs, gru_b_ih, gru_b_hh, hb);
    ushort_t* tmp = ha; ha = hb; hb = tmp;
  }
  scatter_kernel<<<(NDIFF + 255) / 256, 256, 0, stream>>>(diff_idx, flag);
  pool_kernel<<<256, 256, 0, stream>>>(ha, flag, pooled);
  final_kernel<<<1, 256, 0, stream>>>(pooled, fc1_w, fc1_b, fc2_w, fc2_b, w_imp, out);
}

// Round 7
// 426.658 us; speedup vs baseline: 6.2150x; 1.0906x over previous
//
#include <hip/hip_runtime.h>
#include <math.h>

#define NN 100000
#define NE 1200000
#define NDIFF 1000
#define NPART 8
#define PSIZE 12500   // NN / NPART exactly

typedef short short8 __attribute__((ext_vector_type(8)));
typedef float floatx4 __attribute__((ext_vector_type(4)));
typedef float floatx2 __attribute__((ext_vector_type(2)));
typedef unsigned short ushort_t;

__device__ __forceinline__ float softplusf_(float x) {
  return fmaxf(x, 0.f) + logf(1.f + __expf(-fabsf(x)));
}
__device__ __forceinline__ float sigmoidf_(float x) {
  return 1.f / (1.f + __expf(-x));
}
__device__ __forceinline__ float tanhf_fast(float x) {
  float ax = fabsf(x);
  float e = __expf(-2.f * ax);
  float t = (1.f - e) / (1.f + e);
  return x < 0.f ? -t : t;
}
__device__ __forceinline__ ushort_t f2bf(float f) {
  unsigned u = __float_as_uint(f);
  unsigned r = (u + 0x7FFFu + ((u >> 16) & 1u)) >> 16;
  return (ushort_t)r;
}
__device__ __forceinline__ float bf2f(ushort_t s) {
  return __uint_as_float(((unsigned)s) << 16);
}
// pack 8 bf16 (short8) -> 8 fp8 e4m3 bytes (uint2)
__device__ __forceinline__ uint2 bf8_to_fp8x8(short8 v) {
  float f[8];
  #pragma unroll
  for (int i = 0; i < 8; ++i) f[i] = bf2f((ushort_t)v[i]);
  int a = 0, b = 0;
  a = __builtin_amdgcn_cvt_pk_fp8_f32(f[0], f[1], a, false);
  a = __builtin_amdgcn_cvt_pk_fp8_f32(f[2], f[3], a, true);
  b = __builtin_amdgcn_cvt_pk_fp8_f32(f[4], f[5], b, false);
  b = __builtin_amdgcn_cvt_pk_fp8_f32(f[6], f[7], b, true);
  uint2 r; r.x = (unsigned)a; r.y = (unsigned)b;
  return r;
}

// ---------------- setup kernels ----------------

__global__ void zero_kernel(int* __restrict__ p, int n) {
  int i = blockIdx.x * 256 + threadIdx.x;
  if (i < n) p[i] = 0;
}

// rank[e] = arrival index of edge e within its dst bucket; deg accumulates.
__global__ void rank_kernel(const int* __restrict__ dst, int* __restrict__ deg,
                            ushort_t* __restrict__ rank) {
  int e = blockIdx.x * 256 + threadIdx.x;
  if (e < NE) rank[e] = (ushort_t)atomicAdd(&deg[dst[e]], 1);
}

// Fragment-major bf16 weights: B-fragment of (s,ct) = 64 lanes x 8 bf16 (1KB).
__global__ void prep_w_kernel(const float* __restrict__ lin1_w, const float* __restrict__ lin2_w,
                              const float* __restrict__ w_ih, const float* __restrict__ w_hh,
                              const float* __restrict__ etw,
                              ushort_t* __restrict__ W1s, ushort_t* __restrict__ W2s,
                              ushort_t* __restrict__ Wcs, float* __restrict__ wtab) {
  int i = blockIdx.x * 256 + threadIdx.x;  // 0..81919
  if (i < 8) wtab[i] = softplusf_(etw[i]);
  if (i < 32768) {
    int fi = i >> 9, lane = (i >> 3) & 63, j = i & 7;
    int s = fi >> 4, ct = fi & 15;
    int quad = lane >> 4, l15 = lane & 15;
    int col = ct * 16 + l15, k = s * 32 + quad * 8 + j;
    W1s[i] = f2bf(lin1_w[col * 128 + k]);
  } else if (i < 49152) {
    int i2 = i - 32768;
    int fi = i2 >> 9, lane = (i2 >> 3) & 63, j = i2 & 7;
    int s = fi >> 2, ct = fi & 3;
    int quad = lane >> 4, l15 = lane & 15;
    int col = ct * 16 + l15, k = s * 32 + quad * 8 + j;
    W2s[i2] = f2bf(lin2_w[col * 256 + k]);
  } else {
    int i3 = i - 49152;
    int fi = i3 >> 9, lane = (i3 >> 3) & 63, j = i3 & 7;
    int s = fi >> 4, ct = fi & 15;
    int quad = lane >> 4, l15 = lane & 15;
    int jj = ct * 16 + l15, k = s * 32 + quad * 8 + j;
    float v;
    if (jj < 128)      v = (k < 64) ? w_ih[jj * 64 + k] : w_hh[jj * 64 + (k - 64)];
    else if (jj < 192) v = (k < 64) ? w_ih[jj * 64 + k] : 0.f;
    else               v = (k < 64) ? 0.f : w_hh[(jj - 64) * 64 + (k - 64)];
    Wcs[i3] = f2bf(v);
  }
}

// ---------------- exclusive scan (3 kernels) ----------------

__global__ void scanA_kernel(const int* __restrict__ deg, int* __restrict__ rowptr,
                             int* __restrict__ blockSums) {
  int t = threadIdx.x;
  int base = blockIdx.x * 1024 + t * 4;
  int d0 = (base + 0 < NN) ? deg[base + 0] : 0;
  int d1 = (base + 1 < NN) ? deg[base + 1] : 0;
  int d2 = (base + 2 < NN) ? deg[base + 2] : 0;
  int d3 = (base + 3 < NN) ? deg[base + 3] : 0;
  int s = d0 + d1 + d2 + d3;
  int lane = t & 63;
  int incl = s;
  #pragma unroll
  for (int o = 1; o < 64; o <<= 1) {
    int v = __shfl_up(incl, o, 64);
    if (lane >= o) incl += v;
  }
  __shared__ int wsum[4], woff[4];
  if (lane == 63) wsum[t >> 6] = incl;
  __syncthreads();
  if (t == 0) {
    int r = 0;
    for (int w = 0; w < 4; ++w) { woff[w] = r; r += wsum[w]; }
    blockSums[blockIdx.x] = r;
  }
  __syncthreads();
  int run = woff[t >> 6] + incl - s;
  int dd[4] = {d0, d1, d2, d3};
  #pragma unroll
  for (int q = 0; q < 4; ++q) {
    int idx = base + q;
    if (idx <= NN) rowptr[idx] = run;
    run += dd[q];
  }
}

__global__ void scanB_kernel(const int* __restrict__ blockSums, int* __restrict__ blockOff, int nblk) {
  __shared__ int v[128];
  int t = threadIdx.x;
  int mine = (t < nblk) ? blockSums[t] : 0;
  v[t] = mine;
  __syncthreads();
  for (int o = 1; o < 128; o <<= 1) {
    int add = (t >= o) ? v[t - o] : 0;
    __syncthreads();
    v[t] += add;
    __syncthreads();
  }
  if (t < nblk) blockOff[t] = v[t] - mine;
}

__global__ void scanC_kernel(int* __restrict__ rowptr, const int* __restrict__ blockOff) {
  int t = threadIdx.x;
  int base = blockIdx.x * 1024 + t * 4;
  int add = blockOff[blockIdx.x];
  #pragma unroll
  for (int q = 0; q < 4; ++q) {
    int idx = base + q;
    if (idx <= NN) rowptr[idx] += add;
  }
}

// ---------------- partitioned atomic-free CSR fill ----------------
#define SLICE 2048
__global__ void fill_part_kernel(const int* __restrict__ src, const int* __restrict__ dst,
                                 const int* __restrict__ etype, const ushort_t* __restrict__ rank,
                                 const int* __restrict__ rowptr, int* __restrict__ csr) {
  int p = blockIdx.x & 7;
  int base = (blockIdx.x >> 3) * SLICE;
  const int lo = p * PSIZE, hi = lo + PSIZE;
  #pragma unroll
  for (int it = 0; it < SLICE / 256; ++it) {
    int e = base + it * 256 + threadIdx.x;
    if (e < NE) {
      int d = dst[e];
      if (d >= lo && d < hi) {
        int pos = rowptr[d] + (int)rank[e];
        csr[pos] = src[e] | (etype[e] << 17);
      }
    }
  }
}

// ---------------- fused 2-layer MLP, MFMA bf16, LDS-staged ----------------

__launch_bounds__(256)
__global__ void mlp_kernel(const float* __restrict__ x,
                           const ushort_t* __restrict__ W1s, const float* __restrict__ b1,
                           const ushort_t* __restrict__ W2s, const float* __restrict__ b2,
                           ushort_t* __restrict__ mh, unsigned char* __restrict__ h8) {
  __shared__ ushort_t S[64 * 264];  // 33792 B union
  int t = threadIdx.x;
  int wv = t >> 6, lane = t & 63;
  int quad = lane >> 4, l15 = lane & 15;
  int nb = blockIdx.x * 64;

  #pragma unroll
  for (int it = 0; it < 8; ++it) {
    int f = it * 256 + t;
    int row = f >> 5, off4 = f & 31;
    int grow = min(nb + row, NN - 1);
    float4 v = *(const float4*)&x[(size_t)grow * 128 + off4 * 4];
    union { uint2 d; ushort_t u[4]; } pk;
    pk.u[0] = f2bf(v.x); pk.u[1] = f2bf(v.y); pk.u[2] = f2bf(v.z); pk.u[3] = f2bf(v.w);
    *(uint2*)&S[row * 136 + off4 * 4] = pk.d;
  }
  __syncthreads();

  floatx4 acc1[4][4];
  #pragma unroll
  for (int rt = 0; rt < 4; ++rt)
    #pragma unroll
    for (int c = 0; c < 4; ++c) acc1[rt][c] = (floatx4)0.f;

  #pragma unroll
  for (int s = 0; s < 4; ++s) {
    short8 av[4];
    #pragma unroll
    for (int rt = 0; rt < 4; ++rt)
      av[rt] = *(const short8*)&S[(rt * 16 + l15) * 136 + s * 32 + quad * 8];
    #pragma unroll
    for (int c = 0; c < 4; ++c) {
      short8 bv = *(const short8*)&W1s[((s * 16 + wv * 4 + c) * 64 + lane) * 8];
      #pragma unroll
      for (int rt = 0; rt < 4; ++rt)
        acc1[rt][c] = __builtin_amdgcn_mfma_f32_16x16x32_bf16(av[rt], bv, acc1[rt][c], 0, 0, 0);
    }
  }
  __syncthreads();

  #pragma unroll
  for (int c = 0; c < 4; ++c) {
    int col = (wv * 4 + c) * 16 + l15;
    float bb = b1[col];
    #pragma unroll
    for (int rt = 0; rt < 4; ++rt)
      #pragma unroll
      for (int reg = 0; reg < 4; ++reg)
        S[(rt * 16 + quad * 4 + reg) * 264 + col] = f2bf(fmaxf(acc1[rt][c][reg] + bb, 0.f));
  }
  __syncthreads();

  floatx4 acc2[4];
  #pragma unroll
  for (int c = 0; c < 4; ++c) acc2[c] = (floatx4)0.f;
  #pragma unroll
  for (int s = 0; s < 8; ++s) {
    short8 av = *(const short8*)&S[(wv * 16 + l15) * 264 + s * 32 + quad * 8];
    #pragma unroll
    for (int c = 0; c < 4; ++c) {
      short8 bv = *(const short8*)&W2s[((s * 4 + c) * 64 + lane) * 8];
      acc2[c] = __builtin_amdgcn_mfma_f32_16x16x32_bf16(av, bv, acc2[c], 0, 0, 0);
    }
  }
  __syncthreads();

  #pragma unroll
  for (int c = 0; c < 4; ++c) {
    int col = c * 16 + l15;
    float bb = b2[col];
    #pragma unroll
    for (int reg = 0; reg < 4; ++reg)
      S[(wv * 16 + quad * 4 + reg) * 72 + col] = f2bf(acc2[c][reg] + bb);
  }
  __syncthreads();

  #pragma unroll
  for (int it = 0; it < 2; ++it) {
    int idx = it * 256 + t;
    int row = idx >> 3, ch = idx & 7;
    int node = nb + row;
    if (node < NN) {
      short8 v = *(const short8*)&S[row * 72 + ch * 8];
      *(short8*)&mh[(size_t)node * 128 + 64 + ch * 8] = v;
      *(uint2*)&h8[(size_t)node * 64 + ch * 8] = bf8_to_fp8x8(v);
    }
  }
}

// ---------------- scatter-mean aggregation: fp8 gathers ----------------
// 4 nodes/wave, 16 lanes/node; lane reads one int = 4 fp8 channels -> the 16
// lanes cover the full 64B h8 row (one cache line). 8-edge ILP. m written as
// packed bf16x4. Partition-swizzled for csr L2 locality.

__launch_bounds__(256)
__global__ void agg_kernel(ushort_t* __restrict__ mh, const unsigned char* __restrict__ h8,
                           const int* __restrict__ rowptr,
                           const int* __restrict__ csr, const float* __restrict__ wtab) {
  __shared__ float wt[8];
  if (threadIdx.x < 8) wt[threadIdx.x] = wtab[threadIdx.x];
  __syncthreads();
  int p8 = blockIdx.x & 7, q = blockIdx.x >> 3;
  int local = q * 16 + (threadIdx.x >> 4);
  if (local >= PSIZE) return;
  int node = p8 * PSIZE + local;
  int c4 = threadIdx.x & 15;          // channel group: channels c4*4 .. c4*4+3
  int s = rowptr[node], e = rowptr[node + 1];
  float a0 = 0.f, a1 = 0.f, a2 = 0.f, a3 = 0.f;
  float b0 = 0.f, b1 = 0.f, b2 = 0.f, b3 = 0.f;
  int p = s;
  for (; p + 8 <= e; p += 8) {
    int k[8];
    unsigned v[8];
    #pragma unroll
    for (int i = 0; i < 8; ++i) k[i] = csr[p + i];
    #pragma unroll
    for (int i = 0; i < 8; ++i)
      v[i] = *(const unsigned*)&h8[(size_t)(k[i] & 0x1FFFF) * 64 + c4 * 4];
    #pragma unroll
    for (int i = 0; i < 8; ++i) {
      float w = wt[k[i] >> 17];
      floatx2 lo = __builtin_amdgcn_cvt_pk_f32_fp8((int)v[i], false);
      floatx2 hi = __builtin_amdgcn_cvt_pk_f32_fp8((int)v[i], true);
      if (i & 1) { b0 += w * lo[0]; b1 += w * lo[1]; b2 += w * hi[0]; b3 += w * hi[1]; }
      else       { a0 += w * lo[0]; a1 += w * lo[1]; a2 += w * hi[0]; a3 += w * hi[1]; }
    }
  }
  for (; p < e; ++p) {
    int k = csr[p];
    unsigned v = *(const unsigned*)&h8[(size_t)(k & 0x1FFFF) * 64 + c4 * 4];
    float w = wt[k >> 17];
    floatx2 lo = __builtin_amdgcn_cvt_pk_f32_fp8((int)v, false);
    floatx2 hi = __builtin_amdgcn_cvt_pk_f32_fp8((int)v, true);
    a0 += w * lo[0]; a1 += w * lo[1]; a2 += w * hi[0]; a3 += w * hi[1];
  }
  float invd = 1.f / fmaxf((float)(e - s), 1.f);
  union { uint2 d; ushort_t u[4]; } pk;
  pk.u[0] = f2bf((a0 + b0) * invd);
  pk.u[1] = f2bf((a1 + b1) * invd);
  pk.u[2] = f2bf((a2 + b2) * invd);
  pk.u[3] = f2bf((a3 + b3) * invd);
  *(uint2*)&mh[(size_t)node * 128 + c4 * 4] = pk.d;
}

// ---------------- GRU: MFMA GEMM, LDS-staged A + coalesced out ----------------

__launch_bounds__(256)
__global__ void gru_kernel(const ushort_t* __restrict__ mhin, const ushort_t* __restrict__ Wcs,
                           const float* __restrict__ b_ih, const float* __restrict__ b_hh,
                           ushort_t* __restrict__ mhout, unsigned char* __restrict__ h8) {
  __shared__ ushort_t As[64 * 136];
  __shared__ ushort_t Os[64 * 72];
  int t = threadIdx.x;
  int wv = t >> 6, lane = t & 63;
  int quad = lane >> 4, l15 = lane & 15;
  int nb = blockIdx.x * 64;

  #pragma unroll
  for (int it = 0; it < 4; ++it) {
    int idx = it * 256 + t;
    int row = idx >> 4, ch = idx & 15;
    int grow = min(nb + row, NN - 1);
    short8 v = *(const short8*)&mhin[(size_t)grow * 128 + ch * 8];
    *(short8*)&As[row * 136 + ch * 8] = v;
  }
  __syncthreads();

  floatx4 acc[4][4];
  #pragma unroll
  for (int rt = 0; rt < 4; ++rt)
    #pragma unroll
    for (int g = 0; g < 4; ++g) acc[rt][g] = (floatx4)0.f;

  #pragma unroll
  for (int s = 0; s < 4; ++s) {
    short8 av[4];
    #pragma unroll
    for (int rt = 0; rt < 4; ++rt)
      av[rt] = *(const short8*)&As[(rt * 16 + l15) * 136 + s * 32 + quad * 8];
    #pragma unroll
    for (int g = 0; g < 4; ++g) {
      short8 bv = *(const short8*)&Wcs[((s * 16 + g * 4 + wv) * 64 + lane) * 8];
      #pragma unroll
      for (int rt = 0; rt < 4; ++rt)
        acc[rt][g] = __builtin_amdgcn_mfma_f32_16x16x32_bf16(av[rt], bv, acc[rt][g], 0, 0, 0);
    }
  }

  int j = wv * 16 + l15;
  float bir = b_ih[j] + b_hh[j];
  float biz = b_ih[64 + j] + b_hh[64 + j];
  float bin_ = b_ih[128 + j];
  float bhn = b_hh[128 + j];
  #pragma unroll
  for (int rt = 0; rt < 4; ++rt) {
    #pragma unroll
    for (int reg = 0; reg < 4; ++reg) {
      int lrow = rt * 16 + quad * 4 + reg;
      float r = sigmoidf_(acc[rt][0][reg] + bir);
      float z = sigmoidf_(acc[rt][1][reg] + biz);
      float n = tanhf_fast(acc[rt][2][reg] + bin_ + r * (acc[rt][3][reg] + bhn));
      float hp = bf2f(As[lrow * 136 + 64 + j]);
      Os[lrow * 72 + j] = f2bf((1.f - z) * n + z * hp);
    }
  }
  __syncthreads();

  #pragma unroll
  for (int it = 0; it < 2; ++it) {
    int idx = it * 256 + t;
    int row = idx >> 3, ch = idx & 7;
    int node = nb + row;
    if (node < NN) {
      short8 v = *(const short8*)&Os[row * 72 + ch * 8];
      *(short8*)&mhout[(size_t)node * 128 + 64 + ch * 8] = v;
      *(uint2*)&h8[(size_t)node * 64 + ch * 8] = bf8_to_fp8x8(v);
    }
  }
}

// ---------------- pooling + head ----------------

__global__ void scatter_kernel(const int* __restrict__ diff, int* __restrict__ flag) {
  int i = blockIdx.x * 256 + threadIdx.x;
  if (i < NDIFF) flag[diff[i]] = 1;
}

__global__ void pool_kernel(const ushort_t* __restrict__ mh, const int* __restrict__ flag,
                            float* __restrict__ pooled) {
  int gw = (blockIdx.x * 256 + threadIdx.x) >> 6;
  int lane = threadIdx.x & 63;
  const int chunk = (NN + 1023) / 1024;  // 98
  int n0 = gw * chunk;
  int n1 = min(n0 + chunk, NN);
  float base = 0.f, fl = 0.f, cnt = 0.f;
  int n = n0;
  for (; n + 4 <= n1; n += 4) {
    float v0 = bf2f(mh[(size_t)(n + 0) * 128 + 64 + lane]);
    float v1 = bf2f(mh[(size_t)(n + 1) * 128 + 64 + lane]);
    float v2 = bf2f(mh[(size_t)(n + 2) * 128 + 64 + lane]);
    float v3 = bf2f(mh[(size_t)(n + 3) * 128 + 64 + lane]);
    int f0 = flag[n + 0], f1 = flag[n + 1], f2 = flag[n + 2], f3 = flag[n + 3];
    base += (v0 + v1) + (v2 + v3);
    if (f0) { fl += v0; cnt += 1.f; }
    if (f1) { fl += v1; cnt += 1.f; }
    if (f2) { fl += v2; cnt += 1.f; }
    if (f3) { fl += v3; cnt += 1.f; }
  }
  for (; n < n1; ++n) {
    float v = bf2f(mh[(size_t)n * 128 + 64 + lane]);
    base += v;
    if (flag[n]) { fl += v; cnt += 1.f; }
  }
  atomicAdd(&pooled[lane], base);
  atomicAdd(&pooled[64 + lane], fl);
  if (lane == 0) atomicAdd(&pooled[128], cnt);
}

__global__ void final_kernel(const float* __restrict__ pooled,
                             const float* __restrict__ fc1_w, const float* __restrict__ fc1_b,
                             const float* __restrict__ fc2_w, const float* __restrict__ fc2_b,
                             const float* __restrict__ w_imp, float* __restrict__ out) {
  __shared__ float p[64];
  __shared__ float hid[256];
  __shared__ float o[2];
  int t = threadIdx.x;
  float wpos = softplusf_(w_imp[0]);
  if (t < 64) {
    float num = pooled[t] + wpos * pooled[64 + t];
    float den = (float)NN + wpos * pooled[128];
    p[t] = num / den;
  }
  __syncthreads();
  {
    float a = 0.f;
    for (int k = 0; k < 64; ++k) a += p[k] * fc1_w[t * 64 + k];
    hid[t] = fmaxf(a + fc1_b[t], 0.f);
  }
  __syncthreads();
  if (t < 2) {
    float a = 0.f;
    for (int k = 0; k < 256; ++k) a += hid[k] * fc2_w[t * 256 + k];
    o[t] = a + fc2_b[t];
  }
  __syncthreads();
  if (t == 0) {
    float mx = fmaxf(o[0], o[1]);
    float lse = mx + logf(__expf(o[0] - mx) + __expf(o[1] - mx));
    out[0] = o[0] - lse;
    out[1] = o[1] - lse;
  }
}

// ---------------- launch ----------------

extern "C" void kernel_launch(void* const* d_in, const int* in_sizes, int n_in,
                              void* d_out, int out_size, void* d_ws, size_t ws_size,
                              hipStream_t stream) {
  const float* x        = (const float*)d_in[0];
  const int*   ei       = (const int*)d_in[1];
  const int*   etype    = (const int*)d_in[2];
  const int*   diff_idx = (const int*)d_in[3];
  const float* lin1_w   = (const float*)d_in[4];
  const float* lin1_b   = (const float*)d_in[5];
  const float* lin2_w   = (const float*)d_in[6];
  const float* lin2_b   = (const float*)d_in[7];
  const float* gru_w_ih = (const float*)d_in[8];
  const float* gru_w_hh = (const float*)d_in[9];
  const float* gru_b_ih = (const float*)d_in[10];
  const float* gru_b_hh = (const float*)d_in[11];
  const float* etw      = (const float*)d_in[12];
  const float* fc1_w    = (const float*)d_in[13];
  const float* fc1_b    = (const float*)d_in[14];
  const float* fc2_w    = (const float*)d_in[15];
  const float* fc2_b    = (const float*)d_in[16];
  const float* w_imp    = (const float*)d_in[17];
  float* out = (float*)d_out;

  char* ws = (char*)d_ws;
  size_t off = 0;
  auto alloc = [&](size_t bytes) -> void* {
    void* p = ws + off;
    off += (bytes + 255) & ~(size_t)255;
    return p;
  };
  ushort_t* mh0   = (ushort_t*)alloc((size_t)NN * 128 * 2);
  ushort_t* mh1   = (ushort_t*)alloc((size_t)NN * 128 * 2);
  unsigned char* h8 = (unsigned char*)alloc((size_t)NN * 64);
  int*   csr      = (int*)  alloc((size_t)NE * 4);
  ushort_t* rank  = (ushort_t*)alloc((size_t)NE * 2);
  ushort_t* W1s   = (ushort_t*)alloc(128 * 256 * 2);
  ushort_t* W2s   = (ushort_t*)alloc(256 * 64 * 2);
  ushort_t* Wcs   = (ushort_t*)alloc(128 * 256 * 2);
  float* wtab     = (float*)alloc(8 * 4);
  int*   rowptr   = (int*)  alloc((size_t)(NN + 1) * 4);
  int*   blockSums = (int*)alloc(128 * 4);
  int*   blockOff  = (int*)alloc(128 * 4);
  int*   zbase    = (int*)  alloc((size_t)(2 * NN + 129) * 4);
  int* deg    = zbase;
  int* flag   = zbase + NN;
  float* pooled = (float*)(zbase + 2 * NN);

  const int nscan = (NN + 1023) / 1024;              // 98
  const int ngemm = (NN + 63) / 64;                  // 1563
  const int nfill = ((NE + SLICE - 1) / SLICE) * 8;  // 586*8 = 4688
  const int nagg  = ((PSIZE + 15) / 16) * 8;         // 782*8 = 6256

  zero_kernel<<<(2 * NN + 129 + 255) / 256, 256, 0, stream>>>(zbase, 2 * NN + 129);
  prep_w_kernel<<<320, 256, 0, stream>>>(lin1_w, lin2_w, gru_w_ih, gru_w_hh, etw,
                                         W1s, W2s, Wcs, wtab);
  rank_kernel<<<(NE + 255) / 256, 256, 0, stream>>>(ei + NE, deg, rank);
  scanA_kernel<<<nscan, 256, 0, stream>>>(deg, rowptr, blockSums);
  scanB_kernel<<<1, 128, 0, stream>>>(blockSums, blockOff, nscan);
  scanC_kernel<<<nscan, 256, 0, stream>>>(rowptr, blockOff);
  fill_part_kernel<<<nfill, 256, 0, stream>>>(ei, ei + NE, etype, rank, rowptr, csr);
  mlp_kernel<<<ngemm, 256, 0, stream>>>(x, W1s, lin1_b, W2s, lin2_b, mh0, h8);

  ushort_t* ha = mh0;
  ushort_t* hb = mh1;
  for (int it = 0; it < 3; ++it) {
    agg_kernel<<<nagg, 256, 0, stream>>>(ha, h8, rowptr, csr, wtab);
    gru_kernel<<<ngemm, 256, 0, stream>>>(ha, Wcs, gru_b_ih, gru_b_hh, hb, h8);
    ushort_t* tmp = ha; ha = hb; hb = tmp;
  }
  scatter_kernel<<<(NDIFF + 255) / 256, 256, 0, stream>>>(diff_idx, flag);
  pool_kernel<<<256, 256, 0, stream>>>(ha, flag, pooled);
  final_kernel<<<1, 256, 0, stream>>>(pooled, fc1_w, fc1_b, fc2_w, fc2_b, w_imp, out);
}